// Round 1
// baseline (865.032 us; speedup 1.0000x reference)
//
#include <hip/hip_runtime.h>
#include <hip/hip_bf16.h>

#define NN 50000
#define EE 800000

// ---------------- prep: weight transposes (+ attention fold into W1) --------
__global__ __launch_bounds__(256) void k_prep(
    const float* __restrict__ wft, const float* __restrict__ wcv,
    const float* __restrict__ w1,  const float* __restrict__ att,
    const float* __restrict__ w2,
    float* __restrict__ wftT, float* __restrict__ wcvT,
    float* __restrict__ w1t,  float* __restrict__ w2t)
{
    int g = blockIdx.x * 256 + threadIdx.x;
    if (g < 16384) {                      // 128x128
        int o = g >> 7, f = g & 127;
        wftT[f * 128 + o] = wft[g];
        wcvT[f * 128 + o] = wcv[g];
    }
    if (g < 131072) {                     // W1 [256][512] -> W1t [512][256] * att[c]
        int o = g >> 9, c = g & 511;
        w1t[c * 256 + o] = w1[g] * att[c];
    }
    if (g < 32768) {                      // W2 [128][256] -> W2t [256][128]
        int o2 = g >> 8, o = g & 255;
        w2t[o * 128 + o2] = w2[g];
    }
}

// ---------------- fused node GEMMs: h = relu(x Wft^T + bft); msg = h Wcv^T + bcv
__global__ __launch_bounds__(256) void k_ft_conv(
    const float* __restrict__ x,
    const float* __restrict__ wftT, const float* __restrict__ bft,
    const float* __restrict__ wcvT, const float* __restrict__ bcv,
    float* __restrict__ msg)
{
    __shared__ float xs[8192];   // [64][128]
    __shared__ float hs[8192];   // [64][128]
    const int tid = threadIdx.x;
    const int n0 = blockIdx.x * 64;

    #pragma unroll
    for (int i = 0; i < 8; ++i) {
        int lin = tid + i * 256;          // float4 index, 2048 total
        int row = lin >> 5, c4 = lin & 31;
        float4 v = make_float4(0.f, 0.f, 0.f, 0.f);
        if (n0 + row < NN)
            v = *reinterpret_cast<const float4*>(x + (size_t)(n0 + row) * 128 + c4 * 4);
        *reinterpret_cast<float4*>(xs + row * 128 + c4 * 4) = v;
    }
    __syncthreads();

    const int og = tid & 15, ng = tid >> 4;
    const int o0 = og * 8, nb = ng * 4;
    float acc[4][8];
    #pragma unroll
    for (int i = 0; i < 4; ++i)
        #pragma unroll
        for (int j = 0; j < 8; ++j) acc[i][j] = 0.f;

    #pragma unroll 4
    for (int f = 0; f < 128; ++f) {
        float4 w0 = *reinterpret_cast<const float4*>(wftT + f * 128 + o0);
        float4 w1v = *reinterpret_cast<const float4*>(wftT + f * 128 + o0 + 4);
        float wv[8] = {w0.x, w0.y, w0.z, w0.w, w1v.x, w1v.y, w1v.z, w1v.w};
        #pragma unroll
        for (int i = 0; i < 4; ++i) {
            float xv = xs[(nb + i) * 128 + f];
            #pragma unroll
            for (int j = 0; j < 8; ++j) acc[i][j] = fmaf(xv, wv[j], acc[i][j]);
        }
    }
    {
        float4 b0 = *reinterpret_cast<const float4*>(bft + o0);
        float4 b1v = *reinterpret_cast<const float4*>(bft + o0 + 4);
        float bb[8] = {b0.x, b0.y, b0.z, b0.w, b1v.x, b1v.y, b1v.z, b1v.w};
        #pragma unroll
        for (int i = 0; i < 4; ++i)
            #pragma unroll
            for (int j = 0; j < 8; ++j)
                hs[(nb + i) * 128 + o0 + j] = fmaxf(acc[i][j] + bb[j], 0.f);
    }
    __syncthreads();

    #pragma unroll
    for (int i = 0; i < 4; ++i)
        #pragma unroll
        for (int j = 0; j < 8; ++j) acc[i][j] = 0.f;

    #pragma unroll 4
    for (int f = 0; f < 128; ++f) {
        float4 w0 = *reinterpret_cast<const float4*>(wcvT + f * 128 + o0);
        float4 w1v = *reinterpret_cast<const float4*>(wcvT + f * 128 + o0 + 4);
        float wv[8] = {w0.x, w0.y, w0.z, w0.w, w1v.x, w1v.y, w1v.z, w1v.w};
        #pragma unroll
        for (int i = 0; i < 4; ++i) {
            float hv = hs[(nb + i) * 128 + f];
            #pragma unroll
            for (int j = 0; j < 8; ++j) acc[i][j] = fmaf(hv, wv[j], acc[i][j]);
        }
    }
    {
        float4 b0 = *reinterpret_cast<const float4*>(bcv + o0);
        float4 b1v = *reinterpret_cast<const float4*>(bcv + o0 + 4);
        #pragma unroll
        for (int i = 0; i < 4; ++i) {
            int n = n0 + nb + i;
            if (n < NN) {
                float4 v0 = make_float4(acc[i][0] + b0.x, acc[i][1] + b0.y,
                                        acc[i][2] + b0.z, acc[i][3] + b0.w);
                float4 v1 = make_float4(acc[i][4] + b1v.x, acc[i][5] + b1v.y,
                                        acc[i][6] + b1v.z, acc[i][7] + b1v.w);
                *reinterpret_cast<float4*>(msg + (size_t)n * 128 + o0) = v0;
                *reinterpret_cast<float4*>(msg + (size_t)n * 128 + o0 + 4) = v1;
            }
        }
    }
}

// ---------------- edge pass 1: dist max + in-degree counts ------------------
__global__ __launch_bounds__(256) void k_edge_pass1(
    const int* __restrict__ ei, const float* __restrict__ pos,
    unsigned int* __restrict__ dmax, int* __restrict__ counts)
{
    int e = blockIdx.x * 256 + threadIdx.x;
    float dist = 0.f;
    if (e < EE) {
        int s = ei[e], d = ei[EE + e];
        float dx = pos[s * 3 + 0] - pos[d * 3 + 0];
        float dy = pos[s * 3 + 1] - pos[d * 3 + 1];
        float dz = pos[s * 3 + 2] - pos[d * 3 + 2];
        dist = sqrtf(dx * dx + dy * dy + dz * dz);
        atomicAdd(&counts[d], 1);
    }
    #pragma unroll
    for (int o = 32; o >= 1; o >>= 1)
        dist = fmaxf(dist, __shfl_xor(dist, o));
    if ((threadIdx.x & 63) == 0)
        atomicMax(dmax, __float_as_uint(dist));   // dist >= 0: uint order == float order
}

// ---------------- 3-kernel exclusive scan over counts -----------------------
__global__ __launch_bounds__(256) void k_scan1(const int* __restrict__ counts,
    int* __restrict__ loc, int* __restrict__ bsum)
{
    __shared__ int sd[256];
    int i = blockIdx.x * 256 + threadIdx.x;
    int v = (i < NN) ? counts[i] : 0;
    sd[threadIdx.x] = v;
    __syncthreads();
    for (int ofs = 1; ofs < 256; ofs <<= 1) {
        int t = (threadIdx.x >= ofs) ? sd[threadIdx.x - ofs] : 0;
        __syncthreads();
        sd[threadIdx.x] += t;
        __syncthreads();
    }
    int incl = sd[threadIdx.x];
    if (i < NN) loc[i] = incl - v;
    if (threadIdx.x == 255) bsum[blockIdx.x] = incl;
}

__global__ __launch_bounds__(256) void k_scan2(const int* __restrict__ bsum,
    int* __restrict__ bofs, int nb)
{
    __shared__ int sd[256];
    int v = (threadIdx.x < nb) ? bsum[threadIdx.x] : 0;
    sd[threadIdx.x] = v;
    __syncthreads();
    for (int ofs = 1; ofs < 256; ofs <<= 1) {
        int t = (threadIdx.x >= ofs) ? sd[threadIdx.x - ofs] : 0;
        __syncthreads();
        sd[threadIdx.x] += t;
        __syncthreads();
    }
    bofs[threadIdx.x] = sd[threadIdx.x] - v;
}

__global__ __launch_bounds__(256) void k_scan3(const int* __restrict__ loc,
    const int* __restrict__ bofs, int* __restrict__ offs)
{
    int i = blockIdx.x * 256 + threadIdx.x;
    if (i < NN) offs[i] = loc[i] + bofs[blockIdx.x];
    if (i == 0) offs[NN] = EE;
}

// ---------------- edge pass 2: ab factors + CSR fill ------------------------
__global__ __launch_bounds__(256) void k_fill(
    const int* __restrict__ ei, const float* __restrict__ pos,
    const unsigned int* __restrict__ dmaxp,
    const float* __restrict__ vfp, const float* __restrict__ vpar,
    const int* __restrict__ offs, int* __restrict__ cursor,
    int* __restrict__ csrsrc, float4* __restrict__ csrab)
{
    int e = blockIdx.x * 256 + threadIdx.x;
    if (e >= EE) return;
    int s = ei[e], d = ei[EE + e];
    float dx = pos[s * 3 + 0] - pos[d * 3 + 0];
    float dy = pos[s * 3 + 1] - pos[d * 3 + 1];
    float dz = pos[s * 3 + 2] - pos[d * 3 + 2];
    float dist = sqrtf(dx * dx + dy * dy + dz * dz);
    float rinv = 1.f / (dist + 1e-8f);
    float dsum = (dx + dy + dz) * rinv;           // sum of unit-direction comps
    float r = dist / __uint_as_float(*dmaxp);
    float vf = vfp[0];
    float ab[4];
    #pragma unroll
    for (int k = 0; k < 4; ++k) {
        float v = vf * fminf(r, vpar[k]);          // clip(r,0,vmax): r>=0
        ab[k] = sqrtf(1.f - v * v + 1e-8f) / (1.f + v * dsum);
    }
    int slot = offs[d] + atomicAdd(&cursor[d], 1);
    csrsrc[slot] = s;
    csrab[slot] = make_float4(ab[0], ab[1], ab[2], ab[3]);
}

// ---------------- aggregation: one wave per node, all 4 observers fused -----
__global__ __launch_bounds__(256) void k_agg(
    const int* __restrict__ offs, const int* __restrict__ csrsrc,
    const float4* __restrict__ csrab, const float* __restrict__ msg,
    float* __restrict__ agg)
{
    int lane = threadIdx.x & 63;
    int n = blockIdx.x * 4 + (threadIdx.x >> 6);
    if (n >= NN) return;
    int st = offs[n], en = offs[n + 1];
    float a00 = 0, a10 = 0, a20 = 0, a30 = 0, a01 = 0, a11 = 0, a21 = 0, a31 = 0;
    for (int e = st; e < en; ++e) {
        int s = csrsrc[e];
        float4 ab = csrab[e];
        float m0 = msg[(size_t)s * 128 + lane];
        float m1 = msg[(size_t)s * 128 + 64 + lane];
        a00 = fmaf(ab.x, m0, a00); a01 = fmaf(ab.x, m1, a01);
        a10 = fmaf(ab.y, m0, a10); a11 = fmaf(ab.y, m1, a11);
        a20 = fmaf(ab.z, m0, a20); a21 = fmaf(ab.z, m1, a21);
        a30 = fmaf(ab.w, m0, a30); a31 = fmaf(ab.w, m1, a31);
    }
    float* o = agg + (size_t)n * 512 + lane;       // col c = k*128 + h (concat order)
    o[0]   = a00; o[64]  = a01;
    o[128] = a10; o[192] = a11;
    o[256] = a20; o[320] = a21;
    o[384] = a30; o[448] = a31;
}

// ---------------- BN stats: column sums over nodes --------------------------
__global__ __launch_bounds__(256) void k_bnstats(const float* __restrict__ agg,
    float* __restrict__ bn_sum, float* __restrict__ bn_sq)
{
    int c0 = threadIdx.x * 2;
    int r0 = blockIdx.x * 256;
    int rmax = NN - r0; if (rmax > 256) rmax = 256;
    float s0 = 0, s1 = 0, q0 = 0, q1 = 0;
    for (int r = 0; r < rmax; ++r) {
        const float* p = agg + (size_t)(r0 + r) * 512 + c0;
        float v0 = p[0], v1 = p[1];
        s0 += v0; s1 += v1;
        q0 = fmaf(v0, v0, q0); q1 = fmaf(v1, v1, q1);
    }
    atomicAdd(&bn_sum[c0], s0);     atomicAdd(&bn_sum[c0 + 1], s1);
    atomicAdd(&bn_sq[c0], q0);      atomicAdd(&bn_sq[c0 + 1], q1);
}

__global__ __launch_bounds__(256) void k_bnfin(const float* __restrict__ bn_sum,
    const float* __restrict__ bn_sq, const float* __restrict__ bng,
    const float* __restrict__ bnbeta, float* __restrict__ bns, float* __restrict__ bnbv)
{
    int c = blockIdx.x * 256 + threadIdx.x;
    if (c >= 512) return;
    float mean = bn_sum[c] * (1.f / NN);
    float var = bn_sq[c] * (1.f / NN) - mean * mean;   // biased, as reference
    float sc = bng[c] / sqrtf(var + 1e-5f);
    bns[c] = sc;
    bnbv[c] = bnbeta[c] - mean * sc;
}

// ---------------- final fused: BN-apply + GEMM1 + LN + relu + GEMM2 ---------
__global__ __launch_bounds__(256) void k_final(
    const float* __restrict__ agg,
    const float* __restrict__ bns, const float* __restrict__ bnb,
    const float* __restrict__ w1t, const float* __restrict__ b1,
    const float* __restrict__ lng, const float* __restrict__ lnb,
    const float* __restrict__ w2t, const float* __restrict__ b2,
    float* __restrict__ out)
{
    __shared__ float smem[16384];      // 64 KB: zs[32][512]; later ts[32][256]+mu+iv
    float* zs = smem;
    float* ts = smem;                  // aliases zs after GEMM1 barrier
    float* mu_arr = smem + 8192;
    float* iv_arr = smem + 8224;
    const int tid = threadIdx.x;
    const int n0 = blockIdx.x * 32;

    #pragma unroll
    for (int i = 0; i < 16; ++i) {
        int lin = tid + i * 256;        // float4 idx, 4096 total
        int row = lin >> 7, c4 = lin & 127;
        float4 v = make_float4(0.f, 0.f, 0.f, 0.f);
        if (n0 + row < NN) {
            float4 a = *reinterpret_cast<const float4*>(agg + (size_t)(n0 + row) * 512 + c4 * 4);
            float4 s = *reinterpret_cast<const float4*>(bns + c4 * 4);
            float4 b = *reinterpret_cast<const float4*>(bnb + c4 * 4);
            v.x = fmaxf(fmaf(a.x, s.x, b.x), 0.f);
            v.y = fmaxf(fmaf(a.y, s.y, b.y), 0.f);
            v.z = fmaxf(fmaf(a.z, s.z, b.z), 0.f);
            v.w = fmaxf(fmaf(a.w, s.w, b.w), 0.f);
        }
        *reinterpret_cast<float4*>(zs + row * 512 + c4 * 4) = v;
    }
    __syncthreads();

    const int og = tid & 31, ng = tid >> 5;
    const int o0 = og * 8, nb = ng * 4;
    float acc[4][8];
    #pragma unroll
    for (int i = 0; i < 4; ++i)
        #pragma unroll
        for (int j = 0; j < 8; ++j) acc[i][j] = 0.f;

    #pragma unroll 4
    for (int c = 0; c < 512; ++c) {
        float4 w0 = *reinterpret_cast<const float4*>(w1t + c * 256 + o0);
        float4 w1v = *reinterpret_cast<const float4*>(w1t + c * 256 + o0 + 4);
        float wv[8] = {w0.x, w0.y, w0.z, w0.w, w1v.x, w1v.y, w1v.z, w1v.w};
        #pragma unroll
        for (int i = 0; i < 4; ++i) {
            float zv = zs[(nb + i) * 512 + c];
            #pragma unroll
            for (int j = 0; j < 8; ++j) acc[i][j] = fmaf(zv, wv[j], acc[i][j]);
        }
    }
    __syncthreads();   // everyone done reading zs

    {
        float4 ba = *reinterpret_cast<const float4*>(b1 + o0);
        float4 bbx = *reinterpret_cast<const float4*>(b1 + o0 + 4);
        #pragma unroll
        for (int i = 0; i < 4; ++i) {
            float4 t0 = make_float4(acc[i][0] + ba.x, acc[i][1] + ba.y,
                                    acc[i][2] + ba.z, acc[i][3] + ba.w);
            float4 t1 = make_float4(acc[i][4] + bbx.x, acc[i][5] + bbx.y,
                                    acc[i][6] + bbx.z, acc[i][7] + bbx.w);
            *reinterpret_cast<float4*>(ts + (nb + i) * 256 + o0) = t0;
            *reinterpret_cast<float4*>(ts + (nb + i) * 256 + o0 + 4) = t1;
        }
    }
    __syncthreads();

    {
        int node = tid >> 3, part = tid & 7;       // 32 nodes x 8 partials
        const float* p = ts + node * 256 + part * 32;
        float s = 0.f, q = 0.f;
        #pragma unroll
        for (int j = 0; j < 8; ++j) {
            float4 v = *reinterpret_cast<const float4*>(p + j * 4);
            s += v.x + v.y + v.z + v.w;
            q = fmaf(v.x, v.x, q); q = fmaf(v.y, v.y, q);
            q = fmaf(v.z, v.z, q); q = fmaf(v.w, v.w, q);
        }
        #pragma unroll
        for (int o = 1; o < 8; o <<= 1) { s += __shfl_xor(s, o); q += __shfl_xor(q, o); }
        if (part == 0) {
            float mean = s * (1.f / 256.f);
            float var = q * (1.f / 256.f) - mean * mean;
            mu_arr[node] = mean;
            iv_arr[node] = 1.f / sqrtf(var + 1e-5f);
        }
    }
    __syncthreads();

    const int o2 = og * 4;
    float mu[4], iv[4];
    #pragma unroll
    for (int i = 0; i < 4; ++i) { mu[i] = mu_arr[nb + i]; iv[i] = iv_arr[nb + i]; }
    float acc2[4][4];
    #pragma unroll
    for (int i = 0; i < 4; ++i)
        #pragma unroll
        for (int j = 0; j < 4; ++j) acc2[i][j] = 0.f;

    #pragma unroll 4
    for (int o = 0; o < 256; ++o) {
        float g = lng[o], be = lnb[o];
        float4 w = *reinterpret_cast<const float4*>(w2t + o * 128 + o2);
        #pragma unroll
        for (int i = 0; i < 4; ++i) {
            float tv = ts[(nb + i) * 256 + o];
            float rn = fmaxf(fmaf((tv - mu[i]) * iv[i], g, be), 0.f);
            acc2[i][0] = fmaf(rn, w.x, acc2[i][0]);
            acc2[i][1] = fmaf(rn, w.y, acc2[i][1]);
            acc2[i][2] = fmaf(rn, w.z, acc2[i][2]);
            acc2[i][3] = fmaf(rn, w.w, acc2[i][3]);
        }
    }
    {
        float4 bb = *reinterpret_cast<const float4*>(b2 + o2);
        #pragma unroll
        for (int i = 0; i < 4; ++i) {
            int n = n0 + nb + i;
            if (n < NN) {
                float4 v = make_float4(acc2[i][0] + bb.x, acc2[i][1] + bb.y,
                                       acc2[i][2] + bb.z, acc2[i][3] + bb.w);
                *reinterpret_cast<float4*>(out + (size_t)n * 128 + o2) = v;
            }
        }
    }
}

// ---------------------------------------------------------------------------
extern "C" void kernel_launch(void* const* d_in, const int* in_sizes, int n_in,
                              void* d_out, int out_size, void* d_ws, size_t ws_size,
                              hipStream_t stream)
{
    const float* x    = (const float*)d_in[0];
    const int*   ei   = (const int*)d_in[1];
    const float* pos  = (const float*)d_in[2];
    const float* wft  = (const float*)d_in[3];
    const float* bft  = (const float*)d_in[4];
    const float* wcv  = (const float*)d_in[5];
    const float* bcv  = (const float*)d_in[6];
    const float* vfp  = (const float*)d_in[7];
    const float* vpar = (const float*)d_in[8];
    const float* bng  = (const float*)d_in[9];
    const float* bnbe = (const float*)d_in[10];
    const float* att  = (const float*)d_in[11];
    const float* w1   = (const float*)d_in[12];
    const float* b1   = (const float*)d_in[13];
    const float* lng  = (const float*)d_in[14];
    const float* lnb  = (const float*)d_in[15];
    const float* w2   = (const float*)d_in[16];
    const float* b2   = (const float*)d_in[17];
    float* out = (float*)d_out;

    float* ws = (float*)d_ws;
    size_t off = 0;
    float* msg  = ws + off; off += (size_t)NN * 128;
    float* agg  = ws + off; off += (size_t)NN * 512;
    float* wftT = ws + off; off += 16384;
    float* wcvT = ws + off; off += 16384;
    float* w1t  = ws + off; off += 131072;
    float* w2t  = ws + off; off += 32768;
    float* bns  = ws + off; off += 512;
    float* bnbv = ws + off; off += 512;
    float4* csrab = (float4*)(ws + off); off += (size_t)EE * 4;
    int* csrsrc = (int*)(ws + off); off += EE;
    int* offs   = (int*)(ws + off); off += NN + 4;
    int* loc    = (int*)(ws + off); off += NN;
    int* bsum   = (int*)(ws + off); off += 256;
    int* bofs   = (int*)(ws + off); off += 256;
    size_t zstart = off;
    unsigned int* dmax = (unsigned int*)(ws + off); off += 4;
    float* bn_sum = ws + off; off += 512;
    float* bn_sq  = ws + off; off += 512;
    int* counts = (int*)(ws + off); off += NN;
    int* cursor = (int*)(ws + off); off += NN;
    size_t zend = off;

    hipMemsetAsync(ws + zstart, 0, (zend - zstart) * sizeof(float), stream);

    k_prep<<<512, 256, 0, stream>>>(wft, wcv, w1, att, w2, wftT, wcvT, w1t, w2t);
    k_ft_conv<<<782, 256, 0, stream>>>(x, wftT, bft, wcvT, bcv, msg);
    k_edge_pass1<<<3125, 256, 0, stream>>>(ei, pos, dmax, counts);
    k_scan1<<<196, 256, 0, stream>>>(counts, loc, bsum);
    k_scan2<<<1, 256, 0, stream>>>(bsum, bofs, 196);
    k_scan3<<<196, 256, 0, stream>>>(loc, bofs, offs);
    k_fill<<<3125, 256, 0, stream>>>(ei, pos, dmax, vfp, vpar, offs, cursor, csrsrc, csrab);
    k_agg<<<12500, 256, 0, stream>>>(offs, csrsrc, csrab, msg, agg);
    k_bnstats<<<196, 256, 0, stream>>>(agg, bn_sum, bn_sq);
    k_bnfin<<<2, 256, 0, stream>>>(bn_sum, bn_sq, bng, bnbe, bns, bnbv);
    k_final<<<1563, 256, 0, stream>>>(agg, bns, bnbv, w1t, b1, lng, lnb, w2t, b2, out);
}

// Round 2
// 702.923 us; speedup vs baseline: 1.2306x; 1.2306x over previous
//
#include <hip/hip_runtime.h>
#include <hip/hip_bf16.h>

#define NN 50000
#define EE 800000

typedef short short8 __attribute__((ext_vector_type(8)));
typedef float f32x4 __attribute__((ext_vector_type(4)));

union Frag16B { short8 s; int4 i; };

static __device__ __forceinline__ unsigned short f2bf(float f) {
    union { float f; unsigned u; } v; v.f = f;
    unsigned r = v.u + 0x7FFF + ((v.u >> 16) & 1);   // RNE
    return (unsigned short)(r >> 16);
}
static __device__ __forceinline__ float bf2f(unsigned short h) {
    union { unsigned u; float f; } v; v.u = ((unsigned)h) << 16;
    return v.f;
}

// ---------------- prep: fp32 transposes for ft/conv; bf16 casts for W1/W2 ---
__global__ __launch_bounds__(256) void k_prep(
    const float* __restrict__ wft, const float* __restrict__ wcv,
    const float* __restrict__ w1,  const float* __restrict__ att,
    const float* __restrict__ w2,
    float* __restrict__ wftT, float* __restrict__ wcvT,
    unsigned short* __restrict__ w1b, unsigned short* __restrict__ w2b)
{
    int g = blockIdx.x * 256 + threadIdx.x;
    if (g < 16384) {                      // 128x128 fp32 transposes
        int o = g >> 7, f = g & 127;
        wftT[f * 128 + o] = wft[g];
        wcvT[f * 128 + o] = wcv[g];
    }
    if (g < 131072) {                     // W1 [256][512] row-major, fold att[c]
        int c = g & 511;
        w1b[g] = f2bf(w1[g] * att[c]);
    }
    if (g < 32768) {                      // W2 [128][256] row-major
        w2b[g] = f2bf(w2[g]);
    }
}

// ---------------- fused node GEMMs: msg = (relu(x WftT + bft)) WcvT + bcv (bf16 out)
__global__ __launch_bounds__(256) void k_ft_conv(
    const float* __restrict__ x,
    const float* __restrict__ wftT, const float* __restrict__ bft,
    const float* __restrict__ wcvT, const float* __restrict__ bcv,
    unsigned short* __restrict__ msg)
{
    __shared__ float xs[8192];   // [64][128]
    __shared__ float hs[8192];   // [64][128]
    const int tid = threadIdx.x;
    const int n0 = blockIdx.x * 64;

    #pragma unroll
    for (int i = 0; i < 8; ++i) {
        int lin = tid + i * 256;
        int row = lin >> 5, c4 = lin & 31;
        float4 v = make_float4(0.f, 0.f, 0.f, 0.f);
        if (n0 + row < NN)
            v = *reinterpret_cast<const float4*>(x + (size_t)(n0 + row) * 128 + c4 * 4);
        *reinterpret_cast<float4*>(xs + row * 128 + c4 * 4) = v;
    }
    __syncthreads();

    const int og = tid & 15, ng = tid >> 4;
    const int o0 = og * 8, nb = ng * 4;
    float acc[4][8];
    #pragma unroll
    for (int i = 0; i < 4; ++i)
        #pragma unroll
        for (int j = 0; j < 8; ++j) acc[i][j] = 0.f;

    #pragma unroll 4
    for (int f = 0; f < 128; ++f) {
        float4 w0 = *reinterpret_cast<const float4*>(wftT + f * 128 + o0);
        float4 w1v = *reinterpret_cast<const float4*>(wftT + f * 128 + o0 + 4);
        float wv[8] = {w0.x, w0.y, w0.z, w0.w, w1v.x, w1v.y, w1v.z, w1v.w};
        #pragma unroll
        for (int i = 0; i < 4; ++i) {
            float xv = xs[(nb + i) * 128 + f];
            #pragma unroll
            for (int j = 0; j < 8; ++j) acc[i][j] = fmaf(xv, wv[j], acc[i][j]);
        }
    }
    {
        float4 b0 = *reinterpret_cast<const float4*>(bft + o0);
        float4 b1v = *reinterpret_cast<const float4*>(bft + o0 + 4);
        float bb[8] = {b0.x, b0.y, b0.z, b0.w, b1v.x, b1v.y, b1v.z, b1v.w};
        #pragma unroll
        for (int i = 0; i < 4; ++i)
            #pragma unroll
            for (int j = 0; j < 8; ++j)
                hs[(nb + i) * 128 + o0 + j] = fmaxf(acc[i][j] + bb[j], 0.f);
    }
    __syncthreads();

    #pragma unroll
    for (int i = 0; i < 4; ++i)
        #pragma unroll
        for (int j = 0; j < 8; ++j) acc[i][j] = 0.f;

    #pragma unroll 4
    for (int f = 0; f < 128; ++f) {
        float4 w0 = *reinterpret_cast<const float4*>(wcvT + f * 128 + o0);
        float4 w1v = *reinterpret_cast<const float4*>(wcvT + f * 128 + o0 + 4);
        float wv[8] = {w0.x, w0.y, w0.z, w0.w, w1v.x, w1v.y, w1v.z, w1v.w};
        #pragma unroll
        for (int i = 0; i < 4; ++i) {
            float hv = hs[(nb + i) * 128 + f];
            #pragma unroll
            for (int j = 0; j < 8; ++j) acc[i][j] = fmaf(hv, wv[j], acc[i][j]);
        }
    }
    {
        float4 b0 = *reinterpret_cast<const float4*>(bcv + o0);
        float4 b1v = *reinterpret_cast<const float4*>(bcv + o0 + 4);
        float bb[8] = {b0.x, b0.y, b0.z, b0.w, b1v.x, b1v.y, b1v.z, b1v.w};
        #pragma unroll
        for (int i = 0; i < 4; ++i) {
            int n = n0 + nb + i;
            if (n < NN) {
                unsigned int pk[4];
                #pragma unroll
                for (int j = 0; j < 4; ++j) {
                    unsigned short lo = f2bf(acc[i][2 * j] + bb[2 * j]);
                    unsigned short hi = f2bf(acc[i][2 * j + 1] + bb[2 * j + 1]);
                    pk[j] = (unsigned int)lo | ((unsigned int)hi << 16);
                }
                *reinterpret_cast<uint4*>(msg + (size_t)n * 128 + o0) =
                    make_uint4(pk[0], pk[1], pk[2], pk[3]);
            }
        }
    }
}

// ---------------- edge pass 1: dist max + in-degree counts ------------------
__global__ __launch_bounds__(256) void k_edge_pass1(
    const int* __restrict__ ei, const float* __restrict__ pos,
    unsigned int* __restrict__ dmax, int* __restrict__ counts)
{
    int e = blockIdx.x * 256 + threadIdx.x;
    float dist = 0.f;
    if (e < EE) {
        int s = ei[e], d = ei[EE + e];
        float dx = pos[s * 3 + 0] - pos[d * 3 + 0];
        float dy = pos[s * 3 + 1] - pos[d * 3 + 1];
        float dz = pos[s * 3 + 2] - pos[d * 3 + 2];
        dist = sqrtf(dx * dx + dy * dy + dz * dz);
        atomicAdd(&counts[d], 1);
    }
    #pragma unroll
    for (int o = 32; o >= 1; o >>= 1)
        dist = fmaxf(dist, __shfl_xor(dist, o));
    if ((threadIdx.x & 63) == 0)
        atomicMax(dmax, __float_as_uint(dist));
}

// ---------------- 3-kernel exclusive scan over counts -----------------------
__global__ __launch_bounds__(256) void k_scan1(const int* __restrict__ counts,
    int* __restrict__ loc, int* __restrict__ bsum)
{
    __shared__ int sd[256];
    int i = blockIdx.x * 256 + threadIdx.x;
    int v = (i < NN) ? counts[i] : 0;
    sd[threadIdx.x] = v;
    __syncthreads();
    for (int ofs = 1; ofs < 256; ofs <<= 1) {
        int t = (threadIdx.x >= ofs) ? sd[threadIdx.x - ofs] : 0;
        __syncthreads();
        sd[threadIdx.x] += t;
        __syncthreads();
    }
    int incl = sd[threadIdx.x];
    if (i < NN) loc[i] = incl - v;
    if (threadIdx.x == 255) bsum[blockIdx.x] = incl;
}

__global__ __launch_bounds__(256) void k_scan2(const int* __restrict__ bsum,
    int* __restrict__ bofs, int nb)
{
    __shared__ int sd[256];
    int v = (threadIdx.x < nb) ? bsum[threadIdx.x] : 0;
    sd[threadIdx.x] = v;
    __syncthreads();
    for (int ofs = 1; ofs < 256; ofs <<= 1) {
        int t = (threadIdx.x >= ofs) ? sd[threadIdx.x - ofs] : 0;
        __syncthreads();
        sd[threadIdx.x] += t;
        __syncthreads();
    }
    bofs[threadIdx.x] = sd[threadIdx.x] - v;
}

__global__ __launch_bounds__(256) void k_scan3(const int* __restrict__ loc,
    const int* __restrict__ bofs, int* __restrict__ offs)
{
    int i = blockIdx.x * 256 + threadIdx.x;
    if (i < NN) offs[i] = loc[i] + bofs[blockIdx.x];
    if (i == 0) offs[NN] = EE;
}

// ---------------- edge pass 2: ab factors + CSR fill ------------------------
__global__ __launch_bounds__(256) void k_fill(
    const int* __restrict__ ei, const float* __restrict__ pos,
    const unsigned int* __restrict__ dmaxp,
    const float* __restrict__ vfp, const float* __restrict__ vpar,
    const int* __restrict__ offs, int* __restrict__ cursor,
    int* __restrict__ csrsrc, float4* __restrict__ csrab)
{
    int e = blockIdx.x * 256 + threadIdx.x;
    if (e >= EE) return;
    int s = ei[e], d = ei[EE + e];
    float dx = pos[s * 3 + 0] - pos[d * 3 + 0];
    float dy = pos[s * 3 + 1] - pos[d * 3 + 1];
    float dz = pos[s * 3 + 2] - pos[d * 3 + 2];
    float dist = sqrtf(dx * dx + dy * dy + dz * dz);
    float rinv = 1.f / (dist + 1e-8f);
    float dsum = (dx + dy + dz) * rinv;
    float r = dist / __uint_as_float(*dmaxp);
    float vf = vfp[0];
    float ab[4];
    #pragma unroll
    for (int k = 0; k < 4; ++k) {
        float v = vf * fminf(r, vpar[k]);
        ab[k] = sqrtf(1.f - v * v + 1e-8f) / (1.f + v * dsum);
    }
    int slot = offs[d] + atomicAdd(&cursor[d], 1);
    csrsrc[slot] = s;
    csrab[slot] = make_float4(ab[0], ab[1], ab[2], ab[3]);
}

// ---------------- aggregation: one wave per node, bf16 msg gather -----------
__global__ __launch_bounds__(256) void k_agg(
    const int* __restrict__ offs, const int* __restrict__ csrsrc,
    const float4* __restrict__ csrab, const unsigned int* __restrict__ msg,
    float* __restrict__ agg)
{
    int lane = threadIdx.x & 63;
    int n = blockIdx.x * 4 + (threadIdx.x >> 6);
    if (n >= NN) return;
    int st = offs[n], en = offs[n + 1];
    float a00 = 0, a10 = 0, a20 = 0, a30 = 0, a01 = 0, a11 = 0, a21 = 0, a31 = 0;
    for (int e = st; e < en; ++e) {
        int s = csrsrc[e];
        float4 ab = csrab[e];
        unsigned int u = msg[(size_t)s * 64 + lane];   // cols 2*lane, 2*lane+1
        float m0 = __uint_as_float(u << 16);
        float m1 = __uint_as_float(u & 0xFFFF0000u);
        a00 = fmaf(ab.x, m0, a00); a01 = fmaf(ab.x, m1, a01);
        a10 = fmaf(ab.y, m0, a10); a11 = fmaf(ab.y, m1, a11);
        a20 = fmaf(ab.z, m0, a20); a21 = fmaf(ab.z, m1, a21);
        a30 = fmaf(ab.w, m0, a30); a31 = fmaf(ab.w, m1, a31);
    }
    float* o = agg + (size_t)n * 512 + 2 * lane;       // col c = k*128 + h
    *reinterpret_cast<float2*>(o)       = make_float2(a00, a01);
    *reinterpret_cast<float2*>(o + 128) = make_float2(a10, a11);
    *reinterpret_cast<float2*>(o + 256) = make_float2(a20, a21);
    *reinterpret_cast<float2*>(o + 384) = make_float2(a30, a31);
}

// ---------------- BN stats: column sums over nodes --------------------------
__global__ __launch_bounds__(256) void k_bnstats(const float* __restrict__ agg,
    float* __restrict__ bn_sum, float* __restrict__ bn_sq)
{
    int c0 = threadIdx.x * 2;
    int r0 = blockIdx.x * 256;
    int rmax = NN - r0; if (rmax > 256) rmax = 256;
    float s0 = 0, s1 = 0, q0 = 0, q1 = 0;
    for (int r = 0; r < rmax; ++r) {
        const float* p = agg + (size_t)(r0 + r) * 512 + c0;
        float v0 = p[0], v1 = p[1];
        s0 += v0; s1 += v1;
        q0 = fmaf(v0, v0, q0); q1 = fmaf(v1, v1, q1);
    }
    atomicAdd(&bn_sum[c0], s0);     atomicAdd(&bn_sum[c0 + 1], s1);
    atomicAdd(&bn_sq[c0], q0);      atomicAdd(&bn_sq[c0 + 1], q1);
}

__global__ __launch_bounds__(256) void k_bnfin(const float* __restrict__ bn_sum,
    const float* __restrict__ bn_sq, const float* __restrict__ bng,
    const float* __restrict__ bnbeta, float* __restrict__ bns, float* __restrict__ bnbv)
{
    int c = blockIdx.x * 256 + threadIdx.x;
    if (c >= 512) return;
    float mean = bn_sum[c] * (1.f / NN);
    float var = bn_sq[c] * (1.f / NN) - mean * mean;
    float sc = bng[c] / sqrtf(var + 1e-5f);
    bns[c] = sc;
    bnbv[c] = bnbeta[c] - mean * sc;
}

// ---------------- final fused MFMA: BN-apply + GEMM1 + LN + relu + GEMM2 ----
// Block = 4 waves x 64 nodes. Wave owns 16 nodes x full 256-col GEMM1 output,
// so LayerNorm is intra-wave (shuffle reduction). A-frags (z) built on the fly
// from agg with BN scale/shift+relu; t matrix round-trips LDS as bf16.
__global__ __launch_bounds__(256) void k_final(
    const float* __restrict__ agg,
    const float* __restrict__ bns, const float* __restrict__ bnb,
    const unsigned short* __restrict__ w1b, const float* __restrict__ b1,
    const float* __restrict__ lng, const float* __restrict__ lnb,
    const unsigned short* __restrict__ w2b, const float* __restrict__ b2,
    float* __restrict__ out)
{
    __shared__ float s_bns[512], s_bnb[512], s_lng[256], s_lnb[256];
    __shared__ float s_mu[64], s_iv[64];
    __shared__ unsigned short s_ts[4][16][264];    // bf16, row stride 264 (pad 8)

    const int tid = threadIdx.x;
    const int w = tid >> 6, lane = tid & 63;
    const int l15 = lane & 15, g = lane >> 4;       // g in 0..3
    const int n0 = blockIdx.x * 64;

    // stage BN/LN vectors
    s_bns[tid] = bns[tid]; s_bns[tid + 256] = bns[tid + 256];
    s_bnb[tid] = bnb[tid]; s_bnb[tid + 256] = bnb[tid + 256];
    s_lng[tid & 255] = lng[tid & 255];   // each written twice, same value
    s_lnb[tid & 255] = lnb[tid & 255];
    __syncthreads();

    const int rowA = n0 + w * 16 + l15;
    const int arow = rowA < NN ? rowA : NN - 1;
    const float* aggrow = agg + (size_t)arow * 512;

    float b1v[16];
    #pragma unroll
    for (int t = 0; t < 16; ++t) b1v[t] = b1[t * 16 + l15];

    // ---------------- GEMM1: [16x512] @ [512x256] ----------------
    f32x4 acc1[16];
    #pragma unroll
    for (int t = 0; t < 16; ++t) acc1[t] = (f32x4){0.f, 0.f, 0.f, 0.f};

    for (int kk = 0; kk < 16; ++kk) {
        const int kb = kk * 32 + g * 8;
        float4 a0 = *reinterpret_cast<const float4*>(aggrow + kb);
        float4 a1 = *reinterpret_cast<const float4*>(aggrow + kb + 4);
        float4 s0 = *reinterpret_cast<const float4*>(s_bns + kb);
        float4 s1 = *reinterpret_cast<const float4*>(s_bns + kb + 4);
        float4 c0 = *reinterpret_cast<const float4*>(s_bnb + kb);
        float4 c1 = *reinterpret_cast<const float4*>(s_bnb + kb + 4);
        float z[8];
        z[0] = fmaxf(fmaf(a0.x, s0.x, c0.x), 0.f);
        z[1] = fmaxf(fmaf(a0.y, s0.y, c0.y), 0.f);
        z[2] = fmaxf(fmaf(a0.z, s0.z, c0.z), 0.f);
        z[3] = fmaxf(fmaf(a0.w, s0.w, c0.w), 0.f);
        z[4] = fmaxf(fmaf(a1.x, s1.x, c1.x), 0.f);
        z[5] = fmaxf(fmaf(a1.y, s1.y, c1.y), 0.f);
        z[6] = fmaxf(fmaf(a1.z, s1.z, c1.z), 0.f);
        z[7] = fmaxf(fmaf(a1.w, s1.w, c1.w), 0.f);
        short8 af;
        #pragma unroll
        for (int j = 0; j < 8; ++j) af[j] = (short)f2bf(z[j]);

        #pragma unroll
        for (int t = 0; t < 16; ++t) {
            Frag16B bf;
            bf.i = *reinterpret_cast<const int4*>(w1b + (size_t)(t * 16 + l15) * 512 + kb);
            acc1[t] = __builtin_amdgcn_mfma_f32_16x16x32_bf16(af, bf.s, acc1[t], 0, 0, 0);
        }
    }

    // ---------------- bias + LN stats (intra-wave) + stash t to LDS ---------
    float ssum[4] = {0, 0, 0, 0}, sq[4] = {0, 0, 0, 0};
    #pragma unroll
    for (int t = 0; t < 16; ++t) {
        float bv = b1v[t];
        #pragma unroll
        for (int r = 0; r < 4; ++r) {
            float tv = acc1[t][r] + bv;
            ssum[r] += tv;
            sq[r] = fmaf(tv, tv, sq[r]);
            s_ts[w][g * 4 + r][t * 16 + l15] = f2bf(tv);
        }
    }
    #pragma unroll
    for (int m = 1; m < 16; m <<= 1) {
        #pragma unroll
        for (int r = 0; r < 4; ++r) {
            ssum[r] += __shfl_xor(ssum[r], m);
            sq[r]   += __shfl_xor(sq[r], m);
        }
    }
    if (l15 < 4) {
        float sv = l15 == 0 ? ssum[0] : l15 == 1 ? ssum[1] : l15 == 2 ? ssum[2] : ssum[3];
        float qv = l15 == 0 ? sq[0]   : l15 == 1 ? sq[1]   : l15 == 2 ? sq[2]   : sq[3];
        float mean = sv * (1.f / 256.f);
        float var = qv * (1.f / 256.f) - mean * mean;
        s_mu[w * 16 + g * 4 + l15] = mean;
        s_iv[w * 16 + g * 4 + l15] = 1.f / sqrtf(var + 1e-5f);
    }
    __syncthreads();

    // ---------------- GEMM2: relu(LN(t)) [16x256] @ [256x128] ---------------
    const float mu_m = s_mu[w * 16 + l15];
    const float iv_m = s_iv[w * 16 + l15];

    f32x4 acc2[8];
    #pragma unroll
    for (int t = 0; t < 8; ++t) acc2[t] = (f32x4){0.f, 0.f, 0.f, 0.f};

    for (int kk = 0; kk < 8; ++kk) {
        const int kb = kk * 32 + g * 8;
        int4 traw = *reinterpret_cast<const int4*>(&s_ts[w][l15][kb]);
        const unsigned short* tu = reinterpret_cast<const unsigned short*>(&traw);
        float4 g0 = *reinterpret_cast<const float4*>(s_lng + kb);
        float4 g1 = *reinterpret_cast<const float4*>(s_lng + kb + 4);
        float4 e0 = *reinterpret_cast<const float4*>(s_lnb + kb);
        float4 e1 = *reinterpret_cast<const float4*>(s_lnb + kb + 4);
        float gg[8] = {g0.x, g0.y, g0.z, g0.w, g1.x, g1.y, g1.z, g1.w};
        float ee[8] = {e0.x, e0.y, e0.z, e0.w, e1.x, e1.y, e1.z, e1.w};
        short8 af;
        #pragma unroll
        for (int j = 0; j < 8; ++j) {
            float tv = bf2f(tu[j]);
            float rn = fmaxf(fmaf((tv - mu_m) * iv_m, gg[j], ee[j]), 0.f);
            af[j] = (short)f2bf(rn);
        }
        #pragma unroll
        for (int t = 0; t < 8; ++t) {
            Frag16B bf;
            bf.i = *reinterpret_cast<const int4*>(w2b + (size_t)(t * 16 + l15) * 256 + kb);
            acc2[t] = __builtin_amdgcn_mfma_f32_16x16x32_bf16(af, bf.s, acc2[t], 0, 0, 0);
        }
    }

    float b2v[8];
    #pragma unroll
    for (int t = 0; t < 8; ++t) b2v[t] = b2[t * 16 + l15];

    #pragma unroll
    for (int t = 0; t < 8; ++t) {
        #pragma unroll
        for (int r = 0; r < 4; ++r) {
            int n = n0 + w * 16 + g * 4 + r;
            if (n < NN)
                out[(size_t)n * 128 + t * 16 + l15] = acc2[t][r] + b2v[t];
        }
    }
}

// ---------------------------------------------------------------------------
extern "C" void kernel_launch(void* const* d_in, const int* in_sizes, int n_in,
                              void* d_out, int out_size, void* d_ws, size_t ws_size,
                              hipStream_t stream)
{
    const float* x    = (const float*)d_in[0];
    const int*   ei   = (const int*)d_in[1];
    const float* pos  = (const float*)d_in[2];
    const float* wft  = (const float*)d_in[3];
    const float* bft  = (const float*)d_in[4];
    const float* wcv  = (const float*)d_in[5];
    const float* bcv  = (const float*)d_in[6];
    const float* vfp  = (const float*)d_in[7];
    const float* vpar = (const float*)d_in[8];
    const float* bng  = (const float*)d_in[9];
    const float* bnbe = (const float*)d_in[10];
    const float* att  = (const float*)d_in[11];
    const float* w1   = (const float*)d_in[12];
    const float* b1   = (const float*)d_in[13];
    const float* lng  = (const float*)d_in[14];
    const float* lnb  = (const float*)d_in[15];
    const float* w2   = (const float*)d_in[16];
    const float* b2   = (const float*)d_in[17];
    float* out = (float*)d_out;

    float* ws = (float*)d_ws;
    size_t off = 0;
    unsigned short* msg = (unsigned short*)(ws + off); off += (size_t)NN * 64;   // bf16 [N][128]
    float* agg  = ws + off; off += (size_t)NN * 512;
    float* wftT = ws + off; off += 16384;
    float* wcvT = ws + off; off += 16384;
    unsigned short* w1b = (unsigned short*)(ws + off); off += 65536;  // 131072 bf16
    unsigned short* w2b = (unsigned short*)(ws + off); off += 16384;  // 32768 bf16
    float* bns  = ws + off; off += 512;
    float* bnbv = ws + off; off += 512;
    float4* csrab = (float4*)(ws + off); off += (size_t)EE * 4;
    int* csrsrc = (int*)(ws + off); off += EE;
    int* offs   = (int*)(ws + off); off += NN + 4;
    int* loc    = (int*)(ws + off); off += NN;
    int* bsum   = (int*)(ws + off); off += 256;
    int* bofs   = (int*)(ws + off); off += 256;
    size_t zstart = off;
    unsigned int* dmax = (unsigned int*)(ws + off); off += 4;
    float* bn_sum = ws + off; off += 512;
    float* bn_sq  = ws + off; off += 512;
    int* counts = (int*)(ws + off); off += NN;
    int* cursor = (int*)(ws + off); off += NN;
    size_t zend = off;

    hipMemsetAsync(ws + zstart, 0, (zend - zstart) * sizeof(float), stream);

    k_prep<<<512, 256, 0, stream>>>(wft, wcv, w1, att, w2, wftT, wcvT, w1b, w2b);
    k_ft_conv<<<782, 256, 0, stream>>>(x, wftT, bft, wcvT, bcv, msg);
    k_edge_pass1<<<3125, 256, 0, stream>>>(ei, pos, dmax, counts);
    k_scan1<<<196, 256, 0, stream>>>(counts, loc, bsum);
    k_scan2<<<1, 256, 0, stream>>>(bsum, bofs, 196);
    k_scan3<<<196, 256, 0, stream>>>(loc, bofs, offs);
    k_fill<<<3125, 256, 0, stream>>>(ei, pos, dmax, vfp, vpar, offs, cursor, csrsrc, csrab);
    k_agg<<<12500, 256, 0, stream>>>(offs, csrsrc, csrab, (const unsigned int*)msg, agg);
    k_bnstats<<<196, 256, 0, stream>>>(agg, bn_sum, bn_sq);
    k_bnfin<<<2, 256, 0, stream>>>(bn_sum, bn_sq, bng, bnbe, bns, bnbv);
    k_final<<<782, 256, 0, stream>>>(agg, bns, bnbv, w1b, b1, lng, lnb, w2b, b2, out);
}

// Round 3
// 565.501 us; speedup vs baseline: 1.5297x; 1.2430x over previous
//
#include <hip/hip_runtime.h>
#include <hip/hip_bf16.h>

#define NN 50000
#define EE 800000

typedef short short8 __attribute__((ext_vector_type(8)));
typedef float f32x4 __attribute__((ext_vector_type(4)));

union Frag16B { short8 s; int4 i; };

static __device__ __forceinline__ unsigned short f2bf(float f) {
    union { float f; unsigned u; } v; v.f = f;
    unsigned r = v.u + 0x7FFF + ((v.u >> 16) & 1);   // RNE
    return (unsigned short)(r >> 16);
}
static __device__ __forceinline__ float bf_lo(unsigned int u) {
    return __uint_as_float(u << 16);
}
static __device__ __forceinline__ float bf_hi(unsigned int u) {
    return __uint_as_float(u & 0xFFFF0000u);
}
static __device__ __forceinline__ unsigned int pack2(float a, float b) {
    return (unsigned int)f2bf(a) | ((unsigned int)f2bf(b) << 16);
}

// ---------------- prep: fragment-major bf16 weight packing ------------------
// frag element j at lane: W[row = t*16 + (lane&15)][col = kk*32 + (lane>>4)*8 + j]
// packed linear: ((kk*T + t)*64 + lane)*8 + j   (16 B per lane per frag -> coalesced)
__global__ __launch_bounds__(256) void k_prep(
    const float* __restrict__ w1,  const float* __restrict__ att,
    const float* __restrict__ w2,
    const float* __restrict__ wft, const float* __restrict__ wcv,
    unsigned short* __restrict__ w1p, unsigned short* __restrict__ w2p,
    unsigned short* __restrict__ wftp, unsigned short* __restrict__ wcvp)
{
    int gth = blockIdx.x * 256 + threadIdx.x;
    int lane = gth & 63, l15 = lane & 15, gg = lane >> 4;
    if (gth < 16384) {                       // w1p: kk<16, t<16, fold att[col]
        int t = (gth >> 6) & 15, kk = gth >> 10;
        int row = t * 16 + l15, c0 = kk * 32 + gg * 8;
        unsigned int pk[4];
        #pragma unroll
        for (int j = 0; j < 4; ++j) {
            int c = c0 + 2 * j;
            pk[j] = pack2(w1[row * 512 + c] * att[c],
                          w1[row * 512 + c + 1] * att[c + 1]);
        }
        *reinterpret_cast<uint4*>(w1p + (size_t)gth * 8) = make_uint4(pk[0], pk[1], pk[2], pk[3]);
    }
    if (gth < 4096) {                        // w2p: kk<8, t<8
        int t = (gth >> 6) & 7, kk = gth >> 9;
        int row = t * 16 + l15, c0 = kk * 32 + gg * 8;
        unsigned int pk[4];
        #pragma unroll
        for (int j = 0; j < 4; ++j) {
            int c = c0 + 2 * j;
            pk[j] = pack2(w2[row * 256 + c], w2[row * 256 + c + 1]);
        }
        *reinterpret_cast<uint4*>(w2p + (size_t)gth * 8) = make_uint4(pk[0], pk[1], pk[2], pk[3]);
    }
    if (gth < 2048) {                        // wftp / wcvp: kk<4, t<8
        int t = (gth >> 6) & 7, kk = gth >> 9;
        int row = t * 16 + l15, c0 = kk * 32 + gg * 8;
        unsigned int pa[4], pb[4];
        #pragma unroll
        for (int j = 0; j < 4; ++j) {
            int c = c0 + 2 * j;
            pa[j] = pack2(wft[row * 128 + c], wft[row * 128 + c + 1]);
            pb[j] = pack2(wcv[row * 128 + c], wcv[row * 128 + c + 1]);
        }
        *reinterpret_cast<uint4*>(wftp + (size_t)gth * 8) = make_uint4(pa[0], pa[1], pa[2], pa[3]);
        *reinterpret_cast<uint4*>(wcvp + (size_t)gth * 8) = make_uint4(pb[0], pb[1], pb[2], pb[3]);
    }
}

// ---------------- fused node GEMMs (MFMA): msg = (relu(x WftT+bft)) WcvT + bcv
__global__ __launch_bounds__(256) void k_ft_conv(
    const float* __restrict__ x,
    const unsigned short* __restrict__ wftp, const float* __restrict__ bft,
    const unsigned short* __restrict__ wcvp, const float* __restrict__ bcv,
    unsigned int* __restrict__ msg)          // bf16 [NN][128] as uint[NN][64]
{
    __shared__ unsigned int s_x[64 * 68];    // bf16 tile, row stride 68 uints (pad) — reused for out
    __shared__ unsigned short s_h[64 * 136]; // row stride 136 shorts (pad)
    const int tid = threadIdx.x;
    const int w = tid >> 6, lane = tid & 63, l15 = lane & 15, g = lane >> 4;
    const int n0 = blockIdx.x * 64;

    // stage x -> bf16 LDS (coalesced)
    #pragma unroll
    for (int i = 0; i < 8; ++i) {
        int lin = tid + i * 256;             // 2048 float4 slots
        int row = lin >> 5, c4 = lin & 31;
        int ar = (n0 + row < NN) ? n0 + row : NN - 1;
        float4 v = *reinterpret_cast<const float4*>(x + (size_t)ar * 128 + c4 * 4);
        s_x[row * 68 + c4 * 2]     = pack2(v.x, v.y);
        s_x[row * 68 + c4 * 2 + 1] = pack2(v.z, v.w);
    }
    __syncthreads();

    float bftv[8], bcvv[8];
    #pragma unroll
    for (int t = 0; t < 8; ++t) { bftv[t] = bft[t * 16 + l15]; bcvv[t] = bcv[t * 16 + l15]; }

    const int4* Bf = reinterpret_cast<const int4*>(wftp);
    f32x4 acc[8];
    #pragma unroll
    for (int t = 0; t < 8; ++t) acc[t] = (f32x4){0.f, 0.f, 0.f, 0.f};
    #pragma unroll
    for (int kk = 0; kk < 4; ++kk) {
        Frag16B a;
        a.i = *reinterpret_cast<const int4*>(&s_x[(w * 16 + l15) * 68 + kk * 16 + g * 4]);
        #pragma unroll
        for (int t = 0; t < 8; ++t) {
            Frag16B b; b.i = Bf[(kk * 8 + t) * 64 + lane];
            acc[t] = __builtin_amdgcn_mfma_f32_16x16x32_bf16(a.s, b.s, acc[t], 0, 0, 0);
        }
    }
    #pragma unroll
    for (int t = 0; t < 8; ++t)
        #pragma unroll
        for (int r = 0; r < 4; ++r)
            s_h[(w * 16 + g * 4 + r) * 136 + t * 16 + l15] =
                f2bf(fmaxf(acc[t][r] + bftv[t], 0.f));
    __syncthreads();

    const int4* Bc = reinterpret_cast<const int4*>(wcvp);
    #pragma unroll
    for (int t = 0; t < 8; ++t) acc[t] = (f32x4){0.f, 0.f, 0.f, 0.f};
    #pragma unroll
    for (int kk = 0; kk < 4; ++kk) {
        Frag16B a;
        a.i = *reinterpret_cast<const int4*>(&s_h[(w * 16 + l15) * 136 + kk * 32 + g * 8]);
        #pragma unroll
        for (int t = 0; t < 8; ++t) {
            Frag16B b; b.i = Bc[(kk * 8 + t) * 64 + lane];
            acc[t] = __builtin_amdgcn_mfma_f32_16x16x32_bf16(a.s, b.s, acc[t], 0, 0, 0);
        }
    }
    // stash C (bf16) into s_x alias, then coalesced store
    unsigned short* s_o = reinterpret_cast<unsigned short*>(s_x);
    #pragma unroll
    for (int t = 0; t < 8; ++t)
        #pragma unroll
        for (int r = 0; r < 4; ++r)
            s_o[(w * 16 + g * 4 + r) * 136 + t * 16 + l15] = f2bf(acc[t][r] + bcvv[t]);
    __syncthreads();
    #pragma unroll
    for (int i = 0; i < 8; ++i) {
        int lin = tid + i * 256;             // 2048 uint2 slots
        int row = lin >> 5, cu2 = lin & 31;
        if (n0 + row < NN) {
            uint2 v;
            v.x = s_x[row * 68 + cu2 * 2];
            v.y = s_x[row * 68 + cu2 * 2 + 1];
            *reinterpret_cast<uint2*>(msg + (size_t)(n0 + row) * 64 + cu2 * 2) = v;
        }
    }
}

// ---------------- edge pass 1: dist max + in-degree + dist/dsum cache -------
__global__ __launch_bounds__(256) void k_edge_pass1(
    const int* __restrict__ ei, const float* __restrict__ pos,
    unsigned int* __restrict__ dmax, int* __restrict__ counts,
    float* __restrict__ dist_arr, float* __restrict__ dsum_arr)
{
    int e = blockIdx.x * 256 + threadIdx.x;
    float dist = 0.f;
    if (e < EE) {
        int s = ei[e], d = ei[EE + e];
        float dx = pos[s * 3 + 0] - pos[d * 3 + 0];
        float dy = pos[s * 3 + 1] - pos[d * 3 + 1];
        float dz = pos[s * 3 + 2] - pos[d * 3 + 2];
        dist = sqrtf(dx * dx + dy * dy + dz * dz);
        float rinv = 1.f / (dist + 1e-8f);
        dist_arr[e] = dist;
        dsum_arr[e] = (dx + dy + dz) * rinv;
        atomicAdd(&counts[d], 1);
    }
    #pragma unroll
    for (int o = 32; o >= 1; o >>= 1)
        dist = fmaxf(dist, __shfl_xor(dist, o));
    if ((threadIdx.x & 63) == 0)
        atomicMax(dmax, __float_as_uint(dist));
}

// ---------------- 3-kernel exclusive scan over counts -----------------------
__global__ __launch_bounds__(256) void k_scan1(const int* __restrict__ counts,
    int* __restrict__ loc, int* __restrict__ bsum)
{
    __shared__ int sd[256];
    int i = blockIdx.x * 256 + threadIdx.x;
    int v = (i < NN) ? counts[i] : 0;
    sd[threadIdx.x] = v;
    __syncthreads();
    for (int ofs = 1; ofs < 256; ofs <<= 1) {
        int t = (threadIdx.x >= ofs) ? sd[threadIdx.x - ofs] : 0;
        __syncthreads();
        sd[threadIdx.x] += t;
        __syncthreads();
    }
    int incl = sd[threadIdx.x];
    if (i < NN) loc[i] = incl - v;
    if (threadIdx.x == 255) bsum[blockIdx.x] = incl;
}

__global__ __launch_bounds__(256) void k_scan2(const int* __restrict__ bsum,
    int* __restrict__ bofs, int nb)
{
    __shared__ int sd[256];
    int v = (threadIdx.x < nb) ? bsum[threadIdx.x] : 0;
    sd[threadIdx.x] = v;
    __syncthreads();
    for (int ofs = 1; ofs < 256; ofs <<= 1) {
        int t = (threadIdx.x >= ofs) ? sd[threadIdx.x - ofs] : 0;
        __syncthreads();
        sd[threadIdx.x] += t;
        __syncthreads();
    }
    bofs[threadIdx.x] = sd[threadIdx.x] - v;
}

__global__ __launch_bounds__(256) void k_scan3(const int* __restrict__ loc,
    const int* __restrict__ bofs, int* __restrict__ offs)
{
    int i = blockIdx.x * 256 + threadIdx.x;
    if (i < NN) offs[i] = loc[i] + bofs[blockIdx.x];
    if (i == 0) offs[NN] = EE;
}

// ---------------- edge pass 2: ab factors + CSR fill ------------------------
__global__ __launch_bounds__(256) void k_fill(
    const int* __restrict__ ei,
    const float* __restrict__ dist_arr, const float* __restrict__ dsum_arr,
    const unsigned int* __restrict__ dmaxp,
    const float* __restrict__ vfp, const float* __restrict__ vpar,
    const int* __restrict__ offs, int* __restrict__ cursor,
    int* __restrict__ csrsrc, float4* __restrict__ csrab)
{
    int e = blockIdx.x * 256 + threadIdx.x;
    if (e >= EE) return;
    int s = ei[e], d = ei[EE + e];
    float dist = dist_arr[e];
    float dsum = dsum_arr[e];
    float r = dist / __uint_as_float(*dmaxp);
    float vf = vfp[0];
    float ab[4];
    #pragma unroll
    for (int k = 0; k < 4; ++k) {
        float v = vf * fminf(r, vpar[k]);
        ab[k] = sqrtf(1.f - v * v + 1e-8f) / (1.f + v * dsum);
    }
    int slot = offs[d] + atomicAdd(&cursor[d], 1);
    csrsrc[slot] = s;
    csrab[slot] = make_float4(ab[0], ab[1], ab[2], ab[3]);
}

// ---------------- aggregation: one wave per node, bf16 out ------------------
__global__ __launch_bounds__(256) void k_agg(
    const int* __restrict__ offs, const int* __restrict__ csrsrc,
    const float4* __restrict__ csrab, const unsigned int* __restrict__ msg,
    unsigned int* __restrict__ aggb)         // bf16 [NN][512] as uint[NN][256]
{
    int lane = threadIdx.x & 63;
    int n = blockIdx.x * 4 + (threadIdx.x >> 6);
    if (n >= NN) return;
    int st = offs[n], en = offs[n + 1];
    float a00 = 0, a10 = 0, a20 = 0, a30 = 0, a01 = 0, a11 = 0, a21 = 0, a31 = 0;
    for (int e = st; e < en; ++e) {
        int s = csrsrc[e];
        float4 ab = csrab[e];
        unsigned int u = msg[(size_t)s * 64 + lane];   // cols 2*lane, 2*lane+1
        float m0 = bf_lo(u);
        float m1 = bf_hi(u);
        a00 = fmaf(ab.x, m0, a00); a01 = fmaf(ab.x, m1, a01);
        a10 = fmaf(ab.y, m0, a10); a11 = fmaf(ab.y, m1, a11);
        a20 = fmaf(ab.z, m0, a20); a21 = fmaf(ab.z, m1, a21);
        a30 = fmaf(ab.w, m0, a30); a31 = fmaf(ab.w, m1, a31);
    }
    unsigned int* o = aggb + (size_t)n * 256 + lane;   // col c = k*128 + h
    o[0]   = pack2(a00, a01);
    o[64]  = pack2(a10, a11);
    o[128] = pack2(a20, a21);
    o[192] = pack2(a30, a31);
}

// ---------------- BN stats: column sums over nodes (bf16 agg) ---------------
__global__ __launch_bounds__(256) void k_bnstats(const unsigned int* __restrict__ aggb,
    float* __restrict__ bn_sum, float* __restrict__ bn_sq)
{
    int r0 = blockIdx.x * 128;
    int rmax = NN - r0; if (rmax > 128) rmax = 128;
    float s0 = 0, s1 = 0, q0 = 0, q1 = 0;
    for (int r = 0; r < rmax; ++r) {
        unsigned int u = aggb[(size_t)(r0 + r) * 256 + threadIdx.x];
        float v0 = bf_lo(u), v1 = bf_hi(u);
        s0 += v0; s1 += v1;
        q0 = fmaf(v0, v0, q0); q1 = fmaf(v1, v1, q1);
    }
    int c0 = threadIdx.x * 2;
    atomicAdd(&bn_sum[c0], s0);     atomicAdd(&bn_sum[c0 + 1], s1);
    atomicAdd(&bn_sq[c0], q0);      atomicAdd(&bn_sq[c0 + 1], q1);
}

__global__ __launch_bounds__(256) void k_bnfin(const float* __restrict__ bn_sum,
    const float* __restrict__ bn_sq, const float* __restrict__ bng,
    const float* __restrict__ bnbeta, float* __restrict__ bns, float* __restrict__ bnbv)
{
    int c = blockIdx.x * 256 + threadIdx.x;
    if (c >= 512) return;
    float mean = bn_sum[c] * (1.f / NN);
    float var = bn_sq[c] * (1.f / NN) - mean * mean;
    float sc = bng[c] / sqrtf(var + 1e-5f);
    bns[c] = sc;
    bnbv[c] = bnbeta[c] - mean * sc;
}

// ---------------- final fused MFMA: BN-apply + GEMM1 + LN + relu + GEMM2 ----
// z-tile staged to LDS coalesced (BN+relu applied); all B-frags coalesced packed.
__global__ __launch_bounds__(256) void k_final(
    const unsigned int* __restrict__ aggb,
    const float* __restrict__ bns, const float* __restrict__ bnb,
    const unsigned short* __restrict__ w1p, const float* __restrict__ b1,
    const float* __restrict__ lng, const float* __restrict__ lnb,
    const unsigned short* __restrict__ w2p, const float* __restrict__ b2,
    float* __restrict__ out)
{
    __shared__ unsigned int s_z[64 * 260];   // 66560 B; row stride 260 uints (pad 4)
    __shared__ float s_lng[256], s_lnb[256];
    __shared__ float s_mu[64], s_iv[64];
    unsigned short* s_ts = reinterpret_cast<unsigned short*>(s_z);  // [64][264] alias

    const int tid = threadIdx.x;
    const int w = tid >> 6, lane = tid & 63, l15 = lane & 15, g = lane >> 4;
    const int n0 = blockIdx.x * 64;

    s_lng[tid] = lng[tid];
    s_lnb[tid] = lnb[tid];

    // stage z = bf16(relu(agg*scale + shift)) — thread owns col pair (2*tid, 2*tid+1)
    float2 sv = *reinterpret_cast<const float2*>(bns + 2 * tid);
    float2 bv = *reinterpret_cast<const float2*>(bnb + 2 * tid);
    #pragma unroll 8
    for (int i = 0; i < 64; ++i) {
        int ar = (n0 + i < NN) ? n0 + i : NN - 1;
        unsigned int u = aggb[(size_t)ar * 256 + tid];
        float z0 = fmaxf(fmaf(bf_lo(u), sv.x, bv.x), 0.f);
        float z1 = fmaxf(fmaf(bf_hi(u), sv.y, bv.y), 0.f);
        s_z[i * 260 + tid] = pack2(z0, z1);
    }
    __syncthreads();

    float b1v[16];
    #pragma unroll
    for (int t = 0; t < 16; ++t) b1v[t] = b1[t * 16 + l15];

    // ---------------- GEMM1: z [16x512] @ W1t [512x256] ----------------
    const int4* B1 = reinterpret_cast<const int4*>(w1p);
    const unsigned short* zrow =
        reinterpret_cast<const unsigned short*>(s_z) + (w * 16 + l15) * 520;
    f32x4 acc1[16];
    #pragma unroll
    for (int t = 0; t < 16; ++t) acc1[t] = (f32x4){0.f, 0.f, 0.f, 0.f};

    #pragma unroll 2
    for (int kk = 0; kk < 16; ++kk) {
        Frag16B a;
        a.i = *reinterpret_cast<const int4*>(zrow + kk * 32 + g * 8);
        #pragma unroll
        for (int t = 0; t < 16; ++t) {
            Frag16B b; b.i = B1[(kk * 16 + t) * 64 + lane];
            acc1[t] = __builtin_amdgcn_mfma_f32_16x16x32_bf16(a.s, b.s, acc1[t], 0, 0, 0);
        }
    }
    __syncthreads();   // all z reads done before s_ts overwrites the buffer

    // ---------------- bias + LN stats (intra-wave) + stash t to LDS ---------
    float ssum[4] = {0, 0, 0, 0}, sq[4] = {0, 0, 0, 0};
    #pragma unroll
    for (int t = 0; t < 16; ++t) {
        float bvv = b1v[t];
        #pragma unroll
        for (int r = 0; r < 4; ++r) {
            float tv = acc1[t][r] + bvv;
            ssum[r] += tv;
            sq[r] = fmaf(tv, tv, sq[r]);
            s_ts[(w * 16 + g * 4 + r) * 264 + t * 16 + l15] = f2bf(tv);
        }
    }
    #pragma unroll
    for (int m = 1; m < 16; m <<= 1) {
        #pragma unroll
        for (int r = 0; r < 4; ++r) {
            ssum[r] += __shfl_xor(ssum[r], m);
            sq[r]   += __shfl_xor(sq[r], m);
        }
    }
    if (l15 < 4) {
        float svv = l15 == 0 ? ssum[0] : l15 == 1 ? ssum[1] : l15 == 2 ? ssum[2] : ssum[3];
        float qv  = l15 == 0 ? sq[0]   : l15 == 1 ? sq[1]   : l15 == 2 ? sq[2]   : sq[3];
        float mean = svv * (1.f / 256.f);
        float var = qv * (1.f / 256.f) - mean * mean;
        s_mu[w * 16 + g * 4 + l15] = mean;
        s_iv[w * 16 + g * 4 + l15] = 1.f / sqrtf(var + 1e-5f);
    }
    __syncthreads();

    // ---------------- GEMM2: relu(LN(t)) [16x256] @ W2t [256x128] -----------
    const float mu_m = s_mu[w * 16 + l15];
    const float iv_m = s_iv[w * 16 + l15];
    const int4* B2 = reinterpret_cast<const int4*>(w2p);
    const unsigned short* trow = s_ts + (w * 16 + l15) * 264;

    f32x4 acc2[8];
    #pragma unroll
    for (int t = 0; t < 8; ++t) acc2[t] = (f32x4){0.f, 0.f, 0.f, 0.f};

    #pragma unroll 2
    for (int kk = 0; kk < 8; ++kk) {
        const int kb = kk * 32 + g * 8;
        int4 traw = *reinterpret_cast<const int4*>(trow + kb);
        const unsigned short* tu = reinterpret_cast<const unsigned short*>(&traw);
        short8 af;
        #pragma unroll
        for (int j = 0; j < 8; ++j) {
            float tv = __uint_as_float(((unsigned int)tu[j]) << 16);
            float rn = fmaxf(fmaf((tv - mu_m) * iv_m, s_lng[kb + j], s_lnb[kb + j]), 0.f);
            af[j] = (short)f2bf(rn);
        }
        #pragma unroll
        for (int t = 0; t < 8; ++t) {
            Frag16B b; b.i = B2[(kk * 8 + t) * 64 + lane];
            acc2[t] = __builtin_amdgcn_mfma_f32_16x16x32_bf16(af, b.s, acc2[t], 0, 0, 0);
        }
    }

    float b2v[8];
    #pragma unroll
    for (int t = 0; t < 8; ++t) b2v[t] = b2[t * 16 + l15];

    #pragma unroll
    for (int t = 0; t < 8; ++t) {
        #pragma unroll
        for (int r = 0; r < 4; ++r) {
            int n = n0 + w * 16 + g * 4 + r;
            if (n < NN)
                out[(size_t)n * 128 + t * 16 + l15] = acc2[t][r] + b2v[t];
        }
    }
}

// ---------------------------------------------------------------------------
extern "C" void kernel_launch(void* const* d_in, const int* in_sizes, int n_in,
                              void* d_out, int out_size, void* d_ws, size_t ws_size,
                              hipStream_t stream)
{
    const float* x    = (const float*)d_in[0];
    const int*   ei   = (const int*)d_in[1];
    const float* pos  = (const float*)d_in[2];
    const float* wft  = (const float*)d_in[3];
    const float* bft  = (const float*)d_in[4];
    const float* wcv  = (const float*)d_in[5];
    const float* bcv  = (const float*)d_in[6];
    const float* vfp  = (const float*)d_in[7];
    const float* vpar = (const float*)d_in[8];
    const float* bng  = (const float*)d_in[9];
    const float* bnbe = (const float*)d_in[10];
    const float* att  = (const float*)d_in[11];
    const float* w1   = (const float*)d_in[12];
    const float* b1   = (const float*)d_in[13];
    const float* lng  = (const float*)d_in[14];
    const float* lnb  = (const float*)d_in[15];
    const float* w2   = (const float*)d_in[16];
    const float* b2   = (const float*)d_in[17];
    float* out = (float*)d_out;

    float* ws = (float*)d_ws;
    size_t off = 0;
    unsigned int* msg  = (unsigned int*)(ws + off); off += (size_t)NN * 64;    // bf16 [N][128]
    unsigned int* aggb = (unsigned int*)(ws + off); off += (size_t)NN * 256;   // bf16 [N][512]
    unsigned short* w1p  = (unsigned short*)(ws + off); off += 65536;  // 131072 bf16
    unsigned short* w2p  = (unsigned short*)(ws + off); off += 16384;  // 32768 bf16
    unsigned short* wftp = (unsigned short*)(ws + off); off += 8192;   // 16384 bf16
    unsigned short* wcvp = (unsigned short*)(ws + off); off += 8192;
    float* bns  = ws + off; off += 512;
    float* bnbv = ws + off; off += 512;
    float* dist_arr = ws + off; off += EE;
    float* dsum_arr = ws + off; off += EE;
    float4* csrab = (float4*)(ws + off); off += (size_t)EE * 4;
    int* csrsrc = (int*)(ws + off); off += EE;
    int* offs   = (int*)(ws + off); off += NN + 4;
    int* loc    = (int*)(ws + off); off += NN;
    int* bsum   = (int*)(ws + off); off += 256;
    int* bofs   = (int*)(ws + off); off += 256;
    size_t zstart = off;
    unsigned int* dmax = (unsigned int*)(ws + off); off += 4;
    float* bn_sum = ws + off; off += 512;
    float* bn_sq  = ws + off; off += 512;
    int* counts = (int*)(ws + off); off += NN;
    int* cursor = (int*)(ws + off); off += NN;
    size_t zend = off;

    hipMemsetAsync(ws + zstart, 0, (zend - zstart) * sizeof(float), stream);

    k_prep<<<64, 256, 0, stream>>>(w1, att, w2, wft, wcv, w1p, w2p, wftp, wcvp);
    k_ft_conv<<<782, 256, 0, stream>>>(x, wftp, bft, wcvp, bcv, msg);
    k_edge_pass1<<<3125, 256, 0, stream>>>(ei, pos, dmax, counts, dist_arr, dsum_arr);
    k_scan1<<<196, 256, 0, stream>>>(counts, loc, bsum);
    k_scan2<<<1, 256, 0, stream>>>(bsum, bofs, 196);
    k_scan3<<<196, 256, 0, stream>>>(loc, bofs, offs);
    k_fill<<<3125, 256, 0, stream>>>(ei, dist_arr, dsum_arr, dmax, vfp, vpar,
                                     offs, cursor, csrsrc, csrab);
    k_agg<<<12500, 256, 0, stream>>>(offs, csrsrc, csrab, msg, aggb);
    k_bnstats<<<392, 256, 0, stream>>>(aggb, bn_sum, bn_sq);
    k_bnfin<<<2, 256, 0, stream>>>(bn_sum, bn_sq, bng, bnbe, bns, bnbv);
    k_final<<<782, 256, 0, stream>>>(aggb, bns, bnbv, w1p, b1, lng, lnb, w2p, b2, out);
}

// Round 4
// 442.292 us; speedup vs baseline: 1.9558x; 1.2786x over previous
//
#include <hip/hip_runtime.h>
#include <hip/hip_bf16.h>

#define NN 50000
#define EE 800000

typedef short short8 __attribute__((ext_vector_type(8)));
typedef float f32x4 __attribute__((ext_vector_type(4)));

union Frag16B { short8 s; int4 i; };
union H4 { _Float16 h[4]; uint2 u; };

static __device__ __forceinline__ unsigned short f2bf(float f) {
    union { float f; unsigned u; } v; v.f = f;
    unsigned r = v.u + 0x7FFF + ((v.u >> 16) & 1);   // RNE
    return (unsigned short)(r >> 16);
}
static __device__ __forceinline__ float bf_lo(unsigned int u) {
    return __uint_as_float(u << 16);
}
static __device__ __forceinline__ float bf_hi(unsigned int u) {
    return __uint_as_float(u & 0xFFFF0000u);
}
static __device__ __forceinline__ unsigned int pack2(float a, float b) {
    return (unsigned int)f2bf(a) | ((unsigned int)f2bf(b) << 16);
}

// ---------------- prep: fragment-major bf16 weight packing + pos->float4 ----
__global__ __launch_bounds__(256) void k_prep(
    const float* __restrict__ w1,  const float* __restrict__ att,
    const float* __restrict__ w2,
    const float* __restrict__ wft, const float* __restrict__ wcv,
    const float* __restrict__ pos,
    unsigned short* __restrict__ w1p, unsigned short* __restrict__ w2p,
    unsigned short* __restrict__ wftp, unsigned short* __restrict__ wcvp,
    float4* __restrict__ pos4)
{
    int gth = blockIdx.x * 256 + threadIdx.x;
    int lane = gth & 63, l15 = lane & 15, gg = lane >> 4;
    if (gth < 16384) {                       // w1p: kk<16, t<16, fold att[col]
        int t = (gth >> 6) & 15, kk = gth >> 10;
        int row = t * 16 + l15, c0 = kk * 32 + gg * 8;
        unsigned int pk[4];
        #pragma unroll
        for (int j = 0; j < 4; ++j) {
            int c = c0 + 2 * j;
            pk[j] = pack2(w1[row * 512 + c] * att[c],
                          w1[row * 512 + c + 1] * att[c + 1]);
        }
        *reinterpret_cast<uint4*>(w1p + (size_t)gth * 8) = make_uint4(pk[0], pk[1], pk[2], pk[3]);
    }
    if (gth < 4096) {                        // w2p: kk<8, t<8
        int t = (gth >> 6) & 7, kk = gth >> 9;
        int row = t * 16 + l15, c0 = kk * 32 + gg * 8;
        unsigned int pk[4];
        #pragma unroll
        for (int j = 0; j < 4; ++j) {
            int c = c0 + 2 * j;
            pk[j] = pack2(w2[row * 256 + c], w2[row * 256 + c + 1]);
        }
        *reinterpret_cast<uint4*>(w2p + (size_t)gth * 8) = make_uint4(pk[0], pk[1], pk[2], pk[3]);
    }
    if (gth < 2048) {                        // wftp / wcvp: kk<4, t<8
        int t = (gth >> 6) & 7, kk = gth >> 9;
        int row = t * 16 + l15, c0 = kk * 32 + gg * 8;
        unsigned int pa[4], pb[4];
        #pragma unroll
        for (int j = 0; j < 4; ++j) {
            int c = c0 + 2 * j;
            pa[j] = pack2(wft[row * 128 + c], wft[row * 128 + c + 1]);
            pb[j] = pack2(wcv[row * 128 + c], wcv[row * 128 + c + 1]);
        }
        *reinterpret_cast<uint4*>(wftp + (size_t)gth * 8) = make_uint4(pa[0], pa[1], pa[2], pa[3]);
        *reinterpret_cast<uint4*>(wcvp + (size_t)gth * 8) = make_uint4(pb[0], pb[1], pb[2], pb[3]);
    }
    if (gth < NN) {                          // pos -> padded float4 (1 gather/endpoint)
        pos4[gth] = make_float4(pos[gth * 3 + 0], pos[gth * 3 + 1], pos[gth * 3 + 2], 0.f);
    }
}

// ---------------- fused node GEMMs (MFMA): msg = (relu(x WftT+bft)) WcvT + bcv
__global__ __launch_bounds__(256) void k_ft_conv(
    const float* __restrict__ x,
    const unsigned short* __restrict__ wftp, const float* __restrict__ bft,
    const unsigned short* __restrict__ wcvp, const float* __restrict__ bcv,
    unsigned int* __restrict__ msg)          // bf16 [NN][128] as uint[NN][64]
{
    __shared__ unsigned int s_x[64 * 68];    // bf16 tile, row stride 68 uints (pad) — reused for out
    __shared__ unsigned short s_h[64 * 136]; // row stride 136 shorts (pad)
    const int tid = threadIdx.x;
    const int w = tid >> 6, lane = tid & 63, l15 = lane & 15, g = lane >> 4;
    const int n0 = blockIdx.x * 64;

    #pragma unroll
    for (int i = 0; i < 8; ++i) {
        int lin = tid + i * 256;             // 2048 float4 slots
        int row = lin >> 5, c4 = lin & 31;
        int ar = (n0 + row < NN) ? n0 + row : NN - 1;
        float4 v = *reinterpret_cast<const float4*>(x + (size_t)ar * 128 + c4 * 4);
        s_x[row * 68 + c4 * 2]     = pack2(v.x, v.y);
        s_x[row * 68 + c4 * 2 + 1] = pack2(v.z, v.w);
    }
    __syncthreads();

    float bftv[8], bcvv[8];
    #pragma unroll
    for (int t = 0; t < 8; ++t) { bftv[t] = bft[t * 16 + l15]; bcvv[t] = bcv[t * 16 + l15]; }

    const int4* Bf = reinterpret_cast<const int4*>(wftp);
    f32x4 acc[8];
    #pragma unroll
    for (int t = 0; t < 8; ++t) acc[t] = (f32x4){0.f, 0.f, 0.f, 0.f};
    #pragma unroll
    for (int kk = 0; kk < 4; ++kk) {
        Frag16B a;
        a.i = *reinterpret_cast<const int4*>(&s_x[(w * 16 + l15) * 68 + kk * 16 + g * 4]);
        #pragma unroll
        for (int t = 0; t < 8; ++t) {
            Frag16B b; b.i = Bf[(kk * 8 + t) * 64 + lane];
            acc[t] = __builtin_amdgcn_mfma_f32_16x16x32_bf16(a.s, b.s, acc[t], 0, 0, 0);
        }
    }
    #pragma unroll
    for (int t = 0; t < 8; ++t)
        #pragma unroll
        for (int r = 0; r < 4; ++r)
            s_h[(w * 16 + g * 4 + r) * 136 + t * 16 + l15] =
                f2bf(fmaxf(acc[t][r] + bftv[t], 0.f));
    __syncthreads();

    const int4* Bc = reinterpret_cast<const int4*>(wcvp);
    #pragma unroll
    for (int t = 0; t < 8; ++t) acc[t] = (f32x4){0.f, 0.f, 0.f, 0.f};
    #pragma unroll
    for (int kk = 0; kk < 4; ++kk) {
        Frag16B a;
        a.i = *reinterpret_cast<const int4*>(&s_h[(w * 16 + l15) * 136 + kk * 32 + g * 8]);
        #pragma unroll
        for (int t = 0; t < 8; ++t) {
            Frag16B b; b.i = Bc[(kk * 8 + t) * 64 + lane];
            acc[t] = __builtin_amdgcn_mfma_f32_16x16x32_bf16(a.s, b.s, acc[t], 0, 0, 0);
        }
    }
    unsigned short* s_o = reinterpret_cast<unsigned short*>(s_x);
    #pragma unroll
    for (int t = 0; t < 8; ++t)
        #pragma unroll
        for (int r = 0; r < 4; ++r)
            s_o[(w * 16 + g * 4 + r) * 136 + t * 16 + l15] = f2bf(acc[t][r] + bcvv[t]);
    __syncthreads();
    #pragma unroll
    for (int i = 0; i < 8; ++i) {
        int lin = tid + i * 256;             // 2048 uint2 slots
        int row = lin >> 5, cu2 = lin & 31;
        if (n0 + row < NN) {
            uint2 v;
            v.x = s_x[row * 68 + cu2 * 2];
            v.y = s_x[row * 68 + cu2 * 2 + 1];
            *reinterpret_cast<uint2*>(msg + (size_t)(n0 + row) * 64 + cu2 * 2) = v;
        }
    }
}

// ---------------- edge pass 1: dist/dsum + in-degree + per-block max --------
__global__ __launch_bounds__(256) void k_edge_pass1(
    const int* __restrict__ ei, const float4* __restrict__ pos4,
    float* __restrict__ blockmax, int* __restrict__ counts,
    float2* __restrict__ dd)
{
    __shared__ float smax[4];
    int e = blockIdx.x * 256 + threadIdx.x;
    float dist = 0.f;
    if (e < EE) {
        int s = ei[e], d = ei[EE + e];
        float4 ps = pos4[s], pd = pos4[d];
        float dx = ps.x - pd.x, dy = ps.y - pd.y, dz = ps.z - pd.z;
        dist = sqrtf(dx * dx + dy * dy + dz * dz);
        float rinv = 1.f / (dist + 1e-8f);
        dd[e] = make_float2(dist, (dx + dy + dz) * rinv);
        atomicAdd(&counts[d], 1);
    }
    float m = dist;
    #pragma unroll
    for (int o = 32; o >= 1; o >>= 1)
        m = fmaxf(m, __shfl_xor(m, o));
    if ((threadIdx.x & 63) == 0) smax[threadIdx.x >> 6] = m;
    __syncthreads();
    if (threadIdx.x == 0)
        blockmax[blockIdx.x] = fmaxf(fmaxf(smax[0], smax[1]), fmaxf(smax[2], smax[3]));
}

// single-block reduce of blockmax -> dmax (no global atomics)
__global__ __launch_bounds__(256) void k_dmax(const float* __restrict__ blockmax,
    float* __restrict__ dmax, int nb)
{
    __shared__ float smax[4];
    float m = 0.f;
    for (int i = threadIdx.x; i < nb; i += 256) m = fmaxf(m, blockmax[i]);
    #pragma unroll
    for (int o = 32; o >= 1; o >>= 1)
        m = fmaxf(m, __shfl_xor(m, o));
    if ((threadIdx.x & 63) == 0) smax[threadIdx.x >> 6] = m;
    __syncthreads();
    if (threadIdx.x == 0)
        dmax[0] = fmaxf(fmaxf(smax[0], smax[1]), fmaxf(smax[2], smax[3]));
}

// ---------------- 3-kernel exclusive scan over counts -----------------------
__global__ __launch_bounds__(256) void k_scan1(const int* __restrict__ counts,
    int* __restrict__ loc, int* __restrict__ bsum)
{
    __shared__ int sd[256];
    int i = blockIdx.x * 256 + threadIdx.x;
    int v = (i < NN) ? counts[i] : 0;
    sd[threadIdx.x] = v;
    __syncthreads();
    for (int ofs = 1; ofs < 256; ofs <<= 1) {
        int t = (threadIdx.x >= ofs) ? sd[threadIdx.x - ofs] : 0;
        __syncthreads();
        sd[threadIdx.x] += t;
        __syncthreads();
    }
    int incl = sd[threadIdx.x];
    if (i < NN) loc[i] = incl - v;
    if (threadIdx.x == 255) bsum[blockIdx.x] = incl;
}

__global__ __launch_bounds__(256) void k_scan2(const int* __restrict__ bsum,
    int* __restrict__ bofs, int nb)
{
    __shared__ int sd[256];
    int v = (threadIdx.x < nb) ? bsum[threadIdx.x] : 0;
    sd[threadIdx.x] = v;
    __syncthreads();
    for (int ofs = 1; ofs < 256; ofs <<= 1) {
        int t = (threadIdx.x >= ofs) ? sd[threadIdx.x - ofs] : 0;
        __syncthreads();
        sd[threadIdx.x] += t;
        __syncthreads();
    }
    bofs[threadIdx.x] = sd[threadIdx.x] - v;
}

__global__ __launch_bounds__(256) void k_scan3(const int* __restrict__ loc,
    const int* __restrict__ bofs, int* __restrict__ offs)
{
    int i = blockIdx.x * 256 + threadIdx.x;
    if (i < NN) offs[i] = loc[i] + bofs[blockIdx.x];
    if (i == 0) offs[NN] = EE;
}

// ---------------- edge pass 2: ab factors (fp16x4) + CSR fill ---------------
__global__ __launch_bounds__(256) void k_fill(
    const int* __restrict__ ei, const float2* __restrict__ dd,
    const float* __restrict__ dmaxp,
    const float* __restrict__ vfp, const float* __restrict__ vpar,
    const int* __restrict__ offs, int* __restrict__ cursor,
    int* __restrict__ csrsrc, uint2* __restrict__ csrab)
{
    int e = blockIdx.x * 256 + threadIdx.x;
    if (e >= EE) return;
    int s = ei[e], d = ei[EE + e];
    float2 v2 = dd[e];
    float r = v2.x / dmaxp[0];
    float dsum = v2.y;
    float vf = vfp[0];
    H4 p;
    #pragma unroll
    for (int k = 0; k < 4; ++k) {
        float v = vf * fminf(r, vpar[k]);
        p.h[k] = (_Float16)(sqrtf(1.f - v * v + 1e-8f) / (1.f + v * dsum));
    }
    int slot = offs[d] + atomicAdd(&cursor[d], 1);
    csrsrc[slot] = s;
    csrab[slot] = p.u;
}

// ---------------- aggregation: one wave per node, bf16 out ------------------
__global__ __launch_bounds__(256) void k_agg(
    const int* __restrict__ offs, const int* __restrict__ csrsrc,
    const uint2* __restrict__ csrab, const unsigned int* __restrict__ msg,
    unsigned int* __restrict__ aggb)         // bf16 [NN][512] as uint[NN][256]
{
    int lane = threadIdx.x & 63;
    int n = blockIdx.x * 4 + (threadIdx.x >> 6);
    if (n >= NN) return;
    int st = offs[n], en = offs[n + 1];
    float a00 = 0, a10 = 0, a20 = 0, a30 = 0, a01 = 0, a11 = 0, a21 = 0, a31 = 0;
    for (int e = st; e < en; ++e) {
        int s = csrsrc[e];
        H4 p; p.u = csrab[e];
        unsigned int u = msg[(size_t)s * 64 + lane];   // cols 2*lane, 2*lane+1
        float m0 = bf_lo(u);
        float m1 = bf_hi(u);
        float abx = (float)p.h[0], aby = (float)p.h[1];
        float abz = (float)p.h[2], abw = (float)p.h[3];
        a00 = fmaf(abx, m0, a00); a01 = fmaf(abx, m1, a01);
        a10 = fmaf(aby, m0, a10); a11 = fmaf(aby, m1, a11);
        a20 = fmaf(abz, m0, a20); a21 = fmaf(abz, m1, a21);
        a30 = fmaf(abw, m0, a30); a31 = fmaf(abw, m1, a31);
    }
    unsigned int* o = aggb + (size_t)n * 256 + lane;   // col c = k*128 + h
    o[0]   = pack2(a00, a01);
    o[64]  = pack2(a10, a11);
    o[128] = pack2(a20, a21);
    o[192] = pack2(a30, a31);
}

// ---------------- BN stats: column sums over nodes (bf16 agg) ---------------
__global__ __launch_bounds__(256) void k_bnstats(const unsigned int* __restrict__ aggb,
    float* __restrict__ bn_sum, float* __restrict__ bn_sq)
{
    int r0 = blockIdx.x * 128;
    int rmax = NN - r0; if (rmax > 128) rmax = 128;
    float s0 = 0, s1 = 0, q0 = 0, q1 = 0;
    for (int r = 0; r < rmax; ++r) {
        unsigned int u = aggb[(size_t)(r0 + r) * 256 + threadIdx.x];
        float v0 = bf_lo(u), v1 = bf_hi(u);
        s0 += v0; s1 += v1;
        q0 = fmaf(v0, v0, q0); q1 = fmaf(v1, v1, q1);
    }
    int c0 = threadIdx.x * 2;
    atomicAdd(&bn_sum[c0], s0);     atomicAdd(&bn_sum[c0 + 1], s1);
    atomicAdd(&bn_sq[c0], q0);      atomicAdd(&bn_sq[c0 + 1], q1);
}

__global__ __launch_bounds__(256) void k_bnfin(const float* __restrict__ bn_sum,
    const float* __restrict__ bn_sq, const float* __restrict__ bng,
    const float* __restrict__ bnbeta, float* __restrict__ bns, float* __restrict__ bnbv)
{
    int c = blockIdx.x * 256 + threadIdx.x;
    if (c >= 512) return;
    float mean = bn_sum[c] * (1.f / NN);
    float var = bn_sq[c] * (1.f / NN) - mean * mean;
    float sc = bng[c] / sqrtf(var + 1e-5f);
    bns[c] = sc;
    bnbv[c] = bnbeta[c] - mean * sc;
}

// ---------------- final fused MFMA: BN-apply + GEMM1 + LN + relu + GEMM2 ----
__global__ __launch_bounds__(256) void k_final(
    const unsigned int* __restrict__ aggb,
    const float* __restrict__ bns, const float* __restrict__ bnb,
    const unsigned short* __restrict__ w1p, const float* __restrict__ b1,
    const float* __restrict__ lng, const float* __restrict__ lnb,
    const unsigned short* __restrict__ w2p, const float* __restrict__ b2,
    float* __restrict__ out)
{
    __shared__ unsigned int s_z[64 * 260];   // 66560 B; row stride 260 uints (pad 4)
    __shared__ float s_lng[256], s_lnb[256];
    __shared__ float s_mu[64], s_iv[64];
    unsigned short* s_ts = reinterpret_cast<unsigned short*>(s_z);  // [64][264] alias

    const int tid = threadIdx.x;
    const int w = tid >> 6, lane = tid & 63, l15 = lane & 15, g = lane >> 4;
    const int n0 = blockIdx.x * 64;

    s_lng[tid] = lng[tid];
    s_lnb[tid] = lnb[tid];

    float2 sv = *reinterpret_cast<const float2*>(bns + 2 * tid);
    float2 bv = *reinterpret_cast<const float2*>(bnb + 2 * tid);
    #pragma unroll 8
    for (int i = 0; i < 64; ++i) {
        int ar = (n0 + i < NN) ? n0 + i : NN - 1;
        unsigned int u = aggb[(size_t)ar * 256 + tid];
        float z0 = fmaxf(fmaf(bf_lo(u), sv.x, bv.x), 0.f);
        float z1 = fmaxf(fmaf(bf_hi(u), sv.y, bv.y), 0.f);
        s_z[i * 260 + tid] = pack2(z0, z1);
    }
    __syncthreads();

    float b1v[16];
    #pragma unroll
    for (int t = 0; t < 16; ++t) b1v[t] = b1[t * 16 + l15];

    const int4* B1 = reinterpret_cast<const int4*>(w1p);
    const unsigned short* zrow =
        reinterpret_cast<const unsigned short*>(s_z) + (w * 16 + l15) * 520;
    f32x4 acc1[16];
    #pragma unroll
    for (int t = 0; t < 16; ++t) acc1[t] = (f32x4){0.f, 0.f, 0.f, 0.f};

    #pragma unroll 2
    for (int kk = 0; kk < 16; ++kk) {
        Frag16B a;
        a.i = *reinterpret_cast<const int4*>(zrow + kk * 32 + g * 8);
        #pragma unroll
        for (int t = 0; t < 16; ++t) {
            Frag16B b; b.i = B1[(kk * 16 + t) * 64 + lane];
            acc1[t] = __builtin_amdgcn_mfma_f32_16x16x32_bf16(a.s, b.s, acc1[t], 0, 0, 0);
        }
    }
    __syncthreads();

    float ssum[4] = {0, 0, 0, 0}, sq[4] = {0, 0, 0, 0};
    #pragma unroll
    for (int t = 0; t < 16; ++t) {
        float bvv = b1v[t];
        #pragma unroll
        for (int r = 0; r < 4; ++r) {
            float tv = acc1[t][r] + bvv;
            ssum[r] += tv;
            sq[r] = fmaf(tv, tv, sq[r]);
            s_ts[(w * 16 + g * 4 + r) * 264 + t * 16 + l15] = f2bf(tv);
        }
    }
    #pragma unroll
    for (int m = 1; m < 16; m <<= 1) {
        #pragma unroll
        for (int r = 0; r < 4; ++r) {
            ssum[r] += __shfl_xor(ssum[r], m);
            sq[r]   += __shfl_xor(sq[r], m);
        }
    }
    if (l15 < 4) {
        float svv = l15 == 0 ? ssum[0] : l15 == 1 ? ssum[1] : l15 == 2 ? ssum[2] : ssum[3];
        float qv  = l15 == 0 ? sq[0]   : l15 == 1 ? sq[1]   : l15 == 2 ? sq[2]   : sq[3];
        float mean = svv * (1.f / 256.f);
        float var = qv * (1.f / 256.f) - mean * mean;
        s_mu[w * 16 + g * 4 + l15] = mean;
        s_iv[w * 16 + g * 4 + l15] = 1.f / sqrtf(var + 1e-5f);
    }
    __syncthreads();

    const float mu_m = s_mu[w * 16 + l15];
    const float iv_m = s_iv[w * 16 + l15];
    const int4* B2 = reinterpret_cast<const int4*>(w2p);
    const unsigned short* trow = s_ts + (w * 16 + l15) * 264;

    f32x4 acc2[8];
    #pragma unroll
    for (int t = 0; t < 8; ++t) acc2[t] = (f32x4){0.f, 0.f, 0.f, 0.f};

    #pragma unroll 2
    for (int kk = 0; kk < 8; ++kk) {
        const int kb = kk * 32 + g * 8;
        int4 traw = *reinterpret_cast<const int4*>(trow + kb);
        const unsigned short* tu = reinterpret_cast<const unsigned short*>(&traw);
        short8 af;
        #pragma unroll
        for (int j = 0; j < 8; ++j) {
            float tv = __uint_as_float(((unsigned int)tu[j]) << 16);
            float rn = fmaxf(fmaf((tv - mu_m) * iv_m, s_lng[kb + j], s_lnb[kb + j]), 0.f);
            af[j] = (short)f2bf(rn);
        }
        #pragma unroll
        for (int t = 0; t < 8; ++t) {
            Frag16B b; b.i = B2[(kk * 8 + t) * 64 + lane];
            acc2[t] = __builtin_amdgcn_mfma_f32_16x16x32_bf16(af, b.s, acc2[t], 0, 0, 0);
        }
    }

    float b2v[8];
    #pragma unroll
    for (int t = 0; t < 8; ++t) b2v[t] = b2[t * 16 + l15];

    #pragma unroll
    for (int t = 0; t < 8; ++t) {
        #pragma unroll
        for (int r = 0; r < 4; ++r) {
            int n = n0 + w * 16 + g * 4 + r;
            if (n < NN)
                out[(size_t)n * 128 + t * 16 + l15] = acc2[t][r] + b2v[t];
        }
    }
}

// ---------------------------------------------------------------------------
extern "C" void kernel_launch(void* const* d_in, const int* in_sizes, int n_in,
                              void* d_out, int out_size, void* d_ws, size_t ws_size,
                              hipStream_t stream)
{
    const float* x    = (const float*)d_in[0];
    const int*   ei   = (const int*)d_in[1];
    const float* pos  = (const float*)d_in[2];
    const float* wft  = (const float*)d_in[3];
    const float* bft  = (const float*)d_in[4];
    const float* wcv  = (const float*)d_in[5];
    const float* bcv  = (const float*)d_in[6];
    const float* vfp  = (const float*)d_in[7];
    const float* vpar = (const float*)d_in[8];
    const float* bng  = (const float*)d_in[9];
    const float* bnbe = (const float*)d_in[10];
    const float* att  = (const float*)d_in[11];
    const float* w1   = (const float*)d_in[12];
    const float* b1   = (const float*)d_in[13];
    const float* lng  = (const float*)d_in[14];
    const float* lnb  = (const float*)d_in[15];
    const float* w2   = (const float*)d_in[16];
    const float* b2   = (const float*)d_in[17];
    float* out = (float*)d_out;

    float* ws = (float*)d_ws;
    size_t off = 0;
    unsigned int* msg  = (unsigned int*)(ws + off); off += (size_t)NN * 64;    // bf16 [N][128]
    unsigned int* aggb = (unsigned int*)(ws + off); off += (size_t)NN * 256;   // bf16 [N][512]
    unsigned short* w1p  = (unsigned short*)(ws + off); off += 65536;
    unsigned short* w2p  = (unsigned short*)(ws + off); off += 16384;
    unsigned short* wftp = (unsigned short*)(ws + off); off += 8192;
    unsigned short* wcvp = (unsigned short*)(ws + off); off += 8192;
    float4* pos4 = (float4*)(ws + off); off += (size_t)NN * 4;
    float* bns  = ws + off; off += 512;
    float* bnbv = ws + off; off += 512;
    float2* dd  = (float2*)(ws + off); off += (size_t)EE * 2;
    uint2* csrab = (uint2*)(ws + off); off += (size_t)EE * 2;   // fp16 x4 per edge
    int* csrsrc = (int*)(ws + off); off += EE;
    int* offs   = (int*)(ws + off); off += NN + 4;
    int* loc    = (int*)(ws + off); off += NN;
    int* bsum   = (int*)(ws + off); off += 256;
    int* bofs   = (int*)(ws + off); off += 256;
    float* blockmax = ws + off; off += 3136;
    float* dmax = ws + off; off += 4;
    size_t zstart = off;
    float* bn_sum = ws + off; off += 512;
    float* bn_sq  = ws + off; off += 512;
    int* counts = (int*)(ws + off); off += NN;
    int* cursor = (int*)(ws + off); off += NN;
    size_t zend = off;

    hipMemsetAsync(ws + zstart, 0, (zend - zstart) * sizeof(float), stream);

    k_prep<<<196, 256, 0, stream>>>(w1, att, w2, wft, wcv, pos, w1p, w2p, wftp, wcvp, pos4);
    k_ft_conv<<<782, 256, 0, stream>>>(x, wftp, bft, wcvp, bcv, msg);
    k_edge_pass1<<<3125, 256, 0, stream>>>(ei, pos4, blockmax, counts, dd);
    k_dmax<<<1, 256, 0, stream>>>(blockmax, dmax, 3125);
    k_scan1<<<196, 256, 0, stream>>>(counts, loc, bsum);
    k_scan2<<<1, 256, 0, stream>>>(bsum, bofs, 196);
    k_scan3<<<196, 256, 0, stream>>>(loc, bofs, offs);
    k_fill<<<3125, 256, 0, stream>>>(ei, dd, dmax, vfp, vpar, offs, cursor, csrsrc, csrab);
    k_agg<<<12500, 256, 0, stream>>>(offs, csrsrc, csrab, msg, aggb);
    k_bnstats<<<392, 256, 0, stream>>>(aggb, bn_sum, bn_sq);
    k_bnfin<<<2, 256, 0, stream>>>(bn_sum, bn_sq, bng, bnbe, bns, bnbv);
    k_final<<<782, 256, 0, stream>>>(aggb, bns, bnbv, w1p, b1, lng, lnb, w2p, b2, out);
}

// Round 5
// 399.752 us; speedup vs baseline: 2.1639x; 1.1064x over previous
//
#include <hip/hip_runtime.h>
#include <hip/hip_bf16.h>

#define NN 50000
#define EE 800000

typedef short short8 __attribute__((ext_vector_type(8)));
typedef float f32x4 __attribute__((ext_vector_type(4)));

union Frag16B { short8 s; int4 i; };
union H4 { _Float16 h[4]; uint2 u; };

static __device__ __forceinline__ unsigned short f2bf(float f) {
    union { float f; unsigned u; } v; v.f = f;
    unsigned r = v.u + 0x7FFF + ((v.u >> 16) & 1);   // RNE
    return (unsigned short)(r >> 16);
}
static __device__ __forceinline__ float bf_lo(unsigned int u) {
    return __uint_as_float(u << 16);
}
static __device__ __forceinline__ float bf_hi(unsigned int u) {
    return __uint_as_float(u & 0xFFFF0000u);
}
static __device__ __forceinline__ unsigned int pack2(float a, float b) {
    return (unsigned int)f2bf(a) | ((unsigned int)f2bf(b) << 16);
}

// ---------------- prep: fragment-major bf16 weight packing + pos->float4 ----
__global__ __launch_bounds__(256) void k_prep(
    const float* __restrict__ w1,  const float* __restrict__ att,
    const float* __restrict__ w2,
    const float* __restrict__ wft, const float* __restrict__ wcv,
    const float* __restrict__ pos,
    unsigned short* __restrict__ w1p, unsigned short* __restrict__ w2p,
    unsigned short* __restrict__ wftp, unsigned short* __restrict__ wcvp,
    float4* __restrict__ pos4)
{
    int gth = blockIdx.x * 256 + threadIdx.x;
    int lane = gth & 63, l15 = lane & 15, gg = lane >> 4;
    if (gth < 16384) {                       // w1p: kk<16, t<16, fold att[col]
        int t = (gth >> 6) & 15, kk = gth >> 10;
        int row = t * 16 + l15, c0 = kk * 32 + gg * 8;
        unsigned int pk[4];
        #pragma unroll
        for (int j = 0; j < 4; ++j) {
            int c = c0 + 2 * j;
            pk[j] = pack2(w1[row * 512 + c] * att[c],
                          w1[row * 512 + c + 1] * att[c + 1]);
        }
        *reinterpret_cast<uint4*>(w1p + (size_t)gth * 8) = make_uint4(pk[0], pk[1], pk[2], pk[3]);
    }
    if (gth < 4096) {                        // w2p: kk<8, t<8
        int t = (gth >> 6) & 7, kk = gth >> 9;
        int row = t * 16 + l15, c0 = kk * 32 + gg * 8;
        unsigned int pk[4];
        #pragma unroll
        for (int j = 0; j < 4; ++j) {
            int c = c0 + 2 * j;
            pk[j] = pack2(w2[row * 256 + c], w2[row * 256 + c + 1]);
        }
        *reinterpret_cast<uint4*>(w2p + (size_t)gth * 8) = make_uint4(pk[0], pk[1], pk[2], pk[3]);
    }
    if (gth < 2048) {                        // wftp / wcvp: kk<4, t<8
        int t = (gth >> 6) & 7, kk = gth >> 9;
        int row = t * 16 + l15, c0 = kk * 32 + gg * 8;
        unsigned int pa[4], pb[4];
        #pragma unroll
        for (int j = 0; j < 4; ++j) {
            int c = c0 + 2 * j;
            pa[j] = pack2(wft[row * 128 + c], wft[row * 128 + c + 1]);
            pb[j] = pack2(wcv[row * 128 + c], wcv[row * 128 + c + 1]);
        }
        *reinterpret_cast<uint4*>(wftp + (size_t)gth * 8) = make_uint4(pa[0], pa[1], pa[2], pa[3]);
        *reinterpret_cast<uint4*>(wcvp + (size_t)gth * 8) = make_uint4(pb[0], pb[1], pb[2], pb[3]);
    }
    if (gth < NN) {                          // pos -> padded float4 (1 gather/endpoint)
        pos4[gth] = make_float4(pos[gth * 3 + 0], pos[gth * 3 + 1], pos[gth * 3 + 2], 0.f);
    }
}

// ---------------- fused node GEMMs (MFMA): msg = (relu(x WftT+bft)) WcvT + bcv
__global__ __launch_bounds__(256) void k_ft_conv(
    const float* __restrict__ x,
    const unsigned short* __restrict__ wftp, const float* __restrict__ bft,
    const unsigned short* __restrict__ wcvp, const float* __restrict__ bcv,
    unsigned int* __restrict__ msg)          // bf16 [NN][128] as uint[NN][64]
{
    __shared__ unsigned int s_x[64 * 68];    // bf16 tile, row stride 68 uints (pad) — reused for out
    __shared__ unsigned short s_h[64 * 136]; // row stride 136 shorts (pad)
    const int tid = threadIdx.x;
    const int w = tid >> 6, lane = tid & 63, l15 = lane & 15, g = lane >> 4;
    const int n0 = blockIdx.x * 64;

    #pragma unroll
    for (int i = 0; i < 8; ++i) {
        int lin = tid + i * 256;             // 2048 float4 slots
        int row = lin >> 5, c4 = lin & 31;
        int ar = (n0 + row < NN) ? n0 + row : NN - 1;
        float4 v = *reinterpret_cast<const float4*>(x + (size_t)ar * 128 + c4 * 4);
        s_x[row * 68 + c4 * 2]     = pack2(v.x, v.y);
        s_x[row * 68 + c4 * 2 + 1] = pack2(v.z, v.w);
    }
    __syncthreads();

    float bftv[8], bcvv[8];
    #pragma unroll
    for (int t = 0; t < 8; ++t) { bftv[t] = bft[t * 16 + l15]; bcvv[t] = bcv[t * 16 + l15]; }

    const int4* Bf = reinterpret_cast<const int4*>(wftp);
    f32x4 acc[8];
    #pragma unroll
    for (int t = 0; t < 8; ++t) acc[t] = (f32x4){0.f, 0.f, 0.f, 0.f};
    #pragma unroll
    for (int kk = 0; kk < 4; ++kk) {
        Frag16B a;
        a.i = *reinterpret_cast<const int4*>(&s_x[(w * 16 + l15) * 68 + kk * 16 + g * 4]);
        #pragma unroll
        for (int t = 0; t < 8; ++t) {
            Frag16B b; b.i = Bf[(kk * 8 + t) * 64 + lane];
            acc[t] = __builtin_amdgcn_mfma_f32_16x16x32_bf16(a.s, b.s, acc[t], 0, 0, 0);
        }
    }
    #pragma unroll
    for (int t = 0; t < 8; ++t)
        #pragma unroll
        for (int r = 0; r < 4; ++r)
            s_h[(w * 16 + g * 4 + r) * 136 + t * 16 + l15] =
                f2bf(fmaxf(acc[t][r] + bftv[t], 0.f));
    __syncthreads();

    const int4* Bc = reinterpret_cast<const int4*>(wcvp);
    #pragma unroll
    for (int t = 0; t < 8; ++t) acc[t] = (f32x4){0.f, 0.f, 0.f, 0.f};
    #pragma unroll
    for (int kk = 0; kk < 4; ++kk) {
        Frag16B a;
        a.i = *reinterpret_cast<const int4*>(&s_h[(w * 16 + l15) * 136 + kk * 32 + g * 8]);
        #pragma unroll
        for (int t = 0; t < 8; ++t) {
            Frag16B b; b.i = Bc[(kk * 8 + t) * 64 + lane];
            acc[t] = __builtin_amdgcn_mfma_f32_16x16x32_bf16(a.s, b.s, acc[t], 0, 0, 0);
        }
    }
    unsigned short* s_o = reinterpret_cast<unsigned short*>(s_x);
    #pragma unroll
    for (int t = 0; t < 8; ++t)
        #pragma unroll
        for (int r = 0; r < 4; ++r)
            s_o[(w * 16 + g * 4 + r) * 136 + t * 16 + l15] = f2bf(acc[t][r] + bcvv[t]);
    __syncthreads();
    #pragma unroll
    for (int i = 0; i < 8; ++i) {
        int lin = tid + i * 256;             // 2048 uint2 slots
        int row = lin >> 5, cu2 = lin & 31;
        if (n0 + row < NN) {
            uint2 v;
            v.x = s_x[row * 68 + cu2 * 2];
            v.y = s_x[row * 68 + cu2 * 2 + 1];
            *reinterpret_cast<uint2*>(msg + (size_t)(n0 + row) * 64 + cu2 * 2) = v;
        }
    }
}

// ---------------- edge pass 1: {dist,dsum,s,d} record + degree + block max --
__global__ __launch_bounds__(256) void k_edge_pass1(
    const int* __restrict__ ei, const float4* __restrict__ pos4,
    float* __restrict__ blockmax, int* __restrict__ counts,
    float4* __restrict__ dde)
{
    __shared__ float smax[4];
    int e = blockIdx.x * 256 + threadIdx.x;       // grid covers EE exactly
    int s = ei[e], d = ei[EE + e];
    float4 ps = pos4[s], pd = pos4[d];
    float dx = ps.x - pd.x, dy = ps.y - pd.y, dz = ps.z - pd.z;
    float dist = sqrtf(dx * dx + dy * dy + dz * dz);
    float rinv = 1.f / (dist + 1e-8f);
    dde[e] = make_float4(dist, (dx + dy + dz) * rinv,
                         __int_as_float(s), __int_as_float(d));
    atomicAdd(&counts[d], 1);

    float m = dist;
    #pragma unroll
    for (int o = 32; o >= 1; o >>= 1)
        m = fmaxf(m, __shfl_xor(m, o));
    if ((threadIdx.x & 63) == 0) smax[threadIdx.x >> 6] = m;
    __syncthreads();
    if (threadIdx.x == 0)
        blockmax[blockIdx.x] = fmaxf(fmaxf(smax[0], smax[1]), fmaxf(smax[2], smax[3]));
}

// ---------------- 3-kernel exclusive scan over counts -----------------------
__global__ __launch_bounds__(256) void k_scan1(const int* __restrict__ counts,
    int* __restrict__ loc, int* __restrict__ bsum)
{
    __shared__ int sd[256];
    int i = blockIdx.x * 256 + threadIdx.x;
    int v = (i < NN) ? counts[i] : 0;
    sd[threadIdx.x] = v;
    __syncthreads();
    for (int ofs = 1; ofs < 256; ofs <<= 1) {
        int t = (threadIdx.x >= ofs) ? sd[threadIdx.x - ofs] : 0;
        __syncthreads();
        sd[threadIdx.x] += t;
        __syncthreads();
    }
    int incl = sd[threadIdx.x];
    if (i < NN) loc[i] = incl - v;
    if (threadIdx.x == 255) bsum[blockIdx.x] = incl;
}

// block 0: exclusive scan of bsum; block 1: dmax reduce over blockmax
__global__ __launch_bounds__(256) void k_scan2dmax(const int* __restrict__ bsum,
    int* __restrict__ bofs, int nb,
    const float* __restrict__ blockmax, float* __restrict__ dmax, int nmb)
{
    if (blockIdx.x == 0) {
        __shared__ int sd[256];
        int v = (threadIdx.x < nb) ? bsum[threadIdx.x] : 0;
        sd[threadIdx.x] = v;
        __syncthreads();
        for (int ofs = 1; ofs < 256; ofs <<= 1) {
            int t = (threadIdx.x >= ofs) ? sd[threadIdx.x - ofs] : 0;
            __syncthreads();
            sd[threadIdx.x] += t;
            __syncthreads();
        }
        bofs[threadIdx.x] = sd[threadIdx.x] - v;
    } else {
        __shared__ float smax[4];
        float m = 0.f;
        for (int i = threadIdx.x; i < nmb; i += 256) m = fmaxf(m, blockmax[i]);
        #pragma unroll
        for (int o = 32; o >= 1; o >>= 1)
            m = fmaxf(m, __shfl_xor(m, o));
        if ((threadIdx.x & 63) == 0) smax[threadIdx.x >> 6] = m;
        __syncthreads();
        if (threadIdx.x == 0)
            dmax[0] = fmaxf(fmaxf(smax[0], smax[1]), fmaxf(smax[2], smax[3]));
    }
}

__global__ __launch_bounds__(256) void k_scan3(const int* __restrict__ loc,
    const int* __restrict__ bofs, int* __restrict__ offs)
{
    int i = blockIdx.x * 256 + threadIdx.x;
    if (i < NN) offs[i] = loc[i] + bofs[blockIdx.x];
    if (i == 0) offs[NN] = EE;
}

// ---------------- edge pass 2: ab factors + packed CSR record ---------------
__global__ __launch_bounds__(256) void k_fill(
    const float4* __restrict__ dde,
    const float* __restrict__ dmaxp,
    const float* __restrict__ vfp, const float* __restrict__ vpar,
    const int* __restrict__ offs, int* __restrict__ cursor,
    uint4* __restrict__ csre)
{
    int e = blockIdx.x * 256 + threadIdx.x;       // grid covers EE exactly
    float4 v4 = dde[e];
    int s = __float_as_int(v4.z), d = __float_as_int(v4.w);
    float r = v4.x / dmaxp[0];
    float dsum = v4.y;
    float vf = vfp[0];
    H4 p;
    #pragma unroll
    for (int k = 0; k < 4; ++k) {
        float v = vf * fminf(r, vpar[k]);
        p.h[k] = (_Float16)(sqrtf(1.f - v * v + 1e-8f) / (1.f + v * dsum));
    }
    int slot = offs[d] + atomicAdd(&cursor[d], 1);
    csre[slot] = make_uint4((unsigned)s, p.u.x, p.u.y, 0u);
}

// ---------------- aggregation: one wave per node, 4x unrolled gathers -------
__global__ __launch_bounds__(256) void k_agg(
    const int* __restrict__ offs, const uint4* __restrict__ csre,
    const unsigned int* __restrict__ msg,
    unsigned int* __restrict__ aggb)         // bf16 [NN][512] as uint[NN][256]
{
    int lane = threadIdx.x & 63;
    int n = blockIdx.x * 4 + (threadIdx.x >> 6);
    if (n >= NN) return;
    int st = offs[n], en = offs[n + 1];
    float a00 = 0, a10 = 0, a20 = 0, a30 = 0, a01 = 0, a11 = 0, a21 = 0, a31 = 0;

    int e = st;
    for (; e + 4 <= en; e += 4) {
        uint4 r0 = csre[e],     r1 = csre[e + 1];
        uint4 r2 = csre[e + 2], r3 = csre[e + 3];
        unsigned int u0 = msg[(size_t)r0.x * 64 + lane];
        unsigned int u1 = msg[(size_t)r1.x * 64 + lane];
        unsigned int u2 = msg[(size_t)r2.x * 64 + lane];
        unsigned int u3 = msg[(size_t)r3.x * 64 + lane];
        H4 p0, p1, p2, p3;
        p0.u = make_uint2(r0.y, r0.z); p1.u = make_uint2(r1.y, r1.z);
        p2.u = make_uint2(r2.y, r2.z); p3.u = make_uint2(r3.y, r3.z);
        float m0, m1;
        m0 = bf_lo(u0); m1 = bf_hi(u0);
        a00 = fmaf((float)p0.h[0], m0, a00); a01 = fmaf((float)p0.h[0], m1, a01);
        a10 = fmaf((float)p0.h[1], m0, a10); a11 = fmaf((float)p0.h[1], m1, a11);
        a20 = fmaf((float)p0.h[2], m0, a20); a21 = fmaf((float)p0.h[2], m1, a21);
        a30 = fmaf((float)p0.h[3], m0, a30); a31 = fmaf((float)p0.h[3], m1, a31);
        m0 = bf_lo(u1); m1 = bf_hi(u1);
        a00 = fmaf((float)p1.h[0], m0, a00); a01 = fmaf((float)p1.h[0], m1, a01);
        a10 = fmaf((float)p1.h[1], m0, a10); a11 = fmaf((float)p1.h[1], m1, a11);
        a20 = fmaf((float)p1.h[2], m0, a20); a21 = fmaf((float)p1.h[2], m1, a21);
        a30 = fmaf((float)p1.h[3], m0, a30); a31 = fmaf((float)p1.h[3], m1, a31);
        m0 = bf_lo(u2); m1 = bf_hi(u2);
        a00 = fmaf((float)p2.h[0], m0, a00); a01 = fmaf((float)p2.h[0], m1, a01);
        a10 = fmaf((float)p2.h[1], m0, a10); a11 = fmaf((float)p2.h[1], m1, a11);
        a20 = fmaf((float)p2.h[2], m0, a20); a21 = fmaf((float)p2.h[2], m1, a21);
        a30 = fmaf((float)p2.h[3], m0, a30); a31 = fmaf((float)p2.h[3], m1, a31);
        m0 = bf_lo(u3); m1 = bf_hi(u3);
        a00 = fmaf((float)p3.h[0], m0, a00); a01 = fmaf((float)p3.h[0], m1, a01);
        a10 = fmaf((float)p3.h[1], m0, a10); a11 = fmaf((float)p3.h[1], m1, a11);
        a20 = fmaf((float)p3.h[2], m0, a20); a21 = fmaf((float)p3.h[2], m1, a21);
        a30 = fmaf((float)p3.h[3], m0, a30); a31 = fmaf((float)p3.h[3], m1, a31);
    }
    for (; e < en; ++e) {
        uint4 rr = csre[e];
        unsigned int u = msg[(size_t)rr.x * 64 + lane];
        H4 p; p.u = make_uint2(rr.y, rr.z);
        float m0 = bf_lo(u), m1 = bf_hi(u);
        a00 = fmaf((float)p.h[0], m0, a00); a01 = fmaf((float)p.h[0], m1, a01);
        a10 = fmaf((float)p.h[1], m0, a10); a11 = fmaf((float)p.h[1], m1, a11);
        a20 = fmaf((float)p.h[2], m0, a20); a21 = fmaf((float)p.h[2], m1, a21);
        a30 = fmaf((float)p.h[3], m0, a30); a31 = fmaf((float)p.h[3], m1, a31);
    }

    unsigned int* o = aggb + (size_t)n * 256 + lane;   // col c = k*128 + h
    o[0]   = pack2(a00, a01);
    o[64]  = pack2(a10, a11);
    o[128] = pack2(a20, a21);
    o[192] = pack2(a30, a31);
}

// ---------------- BN stats: column sums over nodes (bf16 agg) ---------------
__global__ __launch_bounds__(256) void k_bnstats(const unsigned int* __restrict__ aggb,
    float* __restrict__ bn_sum, float* __restrict__ bn_sq)
{
    int r0 = blockIdx.x * 128;
    int rmax = NN - r0; if (rmax > 128) rmax = 128;
    float s0 = 0, s1 = 0, q0 = 0, q1 = 0;
    for (int r = 0; r < rmax; ++r) {
        unsigned int u = aggb[(size_t)(r0 + r) * 256 + threadIdx.x];
        float v0 = bf_lo(u), v1 = bf_hi(u);
        s0 += v0; s1 += v1;
        q0 = fmaf(v0, v0, q0); q1 = fmaf(v1, v1, q1);
    }
    int c0 = threadIdx.x * 2;
    atomicAdd(&bn_sum[c0], s0);     atomicAdd(&bn_sum[c0 + 1], s1);
    atomicAdd(&bn_sq[c0], q0);      atomicAdd(&bn_sq[c0 + 1], q1);
}

__global__ __launch_bounds__(256) void k_bnfin(const float* __restrict__ bn_sum,
    const float* __restrict__ bn_sq, const float* __restrict__ bng,
    const float* __restrict__ bnbeta, float* __restrict__ bns, float* __restrict__ bnbv)
{
    int c = blockIdx.x * 256 + threadIdx.x;
    if (c >= 512) return;
    float mean = bn_sum[c] * (1.f / NN);
    float var = bn_sq[c] * (1.f / NN) - mean * mean;
    float sc = bng[c] / sqrtf(var + 1e-5f);
    bns[c] = sc;
    bnbv[c] = bnbeta[c] - mean * sc;
}

// ---------------- final fused MFMA: BN-apply + GEMM1 + LN + relu + GEMM2 ----
__global__ __launch_bounds__(256) void k_final(
    const unsigned int* __restrict__ aggb,
    const float* __restrict__ bns, const float* __restrict__ bnb,
    const unsigned short* __restrict__ w1p, const float* __restrict__ b1,
    const float* __restrict__ lng, const float* __restrict__ lnb,
    const unsigned short* __restrict__ w2p, const float* __restrict__ b2,
    float* __restrict__ out)
{
    __shared__ unsigned int s_z[64 * 260];   // 66560 B; row stride 260 uints (pad 4)
    __shared__ float s_lng[256], s_lnb[256];
    __shared__ float s_mu[64], s_iv[64];
    unsigned short* s_ts = reinterpret_cast<unsigned short*>(s_z);  // [64][264] alias

    const int tid = threadIdx.x;
    const int w = tid >> 6, lane = tid & 63, l15 = lane & 15, g = lane >> 4;
    const int n0 = blockIdx.x * 64;

    s_lng[tid] = lng[tid];
    s_lnb[tid] = lnb[tid];

    float2 sv = *reinterpret_cast<const float2*>(bns + 2 * tid);
    float2 bv = *reinterpret_cast<const float2*>(bnb + 2 * tid);
    #pragma unroll 8
    for (int i = 0; i < 64; ++i) {
        int ar = (n0 + i < NN) ? n0 + i : NN - 1;
        unsigned int u = aggb[(size_t)ar * 256 + tid];
        float z0 = fmaxf(fmaf(bf_lo(u), sv.x, bv.x), 0.f);
        float z1 = fmaxf(fmaf(bf_hi(u), sv.y, bv.y), 0.f);
        s_z[i * 260 + tid] = pack2(z0, z1);
    }
    __syncthreads();

    float b1v[16];
    #pragma unroll
    for (int t = 0; t < 16; ++t) b1v[t] = b1[t * 16 + l15];

    const int4* B1 = reinterpret_cast<const int4*>(w1p);
    const unsigned short* zrow =
        reinterpret_cast<const unsigned short*>(s_z) + (w * 16 + l15) * 520;
    f32x4 acc1[16];
    #pragma unroll
    for (int t = 0; t < 16; ++t) acc1[t] = (f32x4){0.f, 0.f, 0.f, 0.f};

    #pragma unroll 2
    for (int kk = 0; kk < 16; ++kk) {
        Frag16B a;
        a.i = *reinterpret_cast<const int4*>(zrow + kk * 32 + g * 8);
        #pragma unroll
        for (int t = 0; t < 16; ++t) {
            Frag16B b; b.i = B1[(kk * 16 + t) * 64 + lane];
            acc1[t] = __builtin_amdgcn_mfma_f32_16x16x32_bf16(a.s, b.s, acc1[t], 0, 0, 0);
        }
    }
    __syncthreads();

    float ssum[4] = {0, 0, 0, 0}, sq[4] = {0, 0, 0, 0};
    #pragma unroll
    for (int t = 0; t < 16; ++t) {
        float bvv = b1v[t];
        #pragma unroll
        for (int r = 0; r < 4; ++r) {
            float tv = acc1[t][r] + bvv;
            ssum[r] += tv;
            sq[r] = fmaf(tv, tv, sq[r]);
            s_ts[(w * 16 + g * 4 + r) * 264 + t * 16 + l15] = f2bf(tv);
        }
    }
    #pragma unroll
    for (int m = 1; m < 16; m <<= 1) {
        #pragma unroll
        for (int r = 0; r < 4; ++r) {
            ssum[r] += __shfl_xor(ssum[r], m);
            sq[r]   += __shfl_xor(sq[r], m);
        }
    }
    if (l15 < 4) {
        float svv = l15 == 0 ? ssum[0] : l15 == 1 ? ssum[1] : l15 == 2 ? ssum[2] : ssum[3];
        float qv  = l15 == 0 ? sq[0]   : l15 == 1 ? sq[1]   : l15 == 2 ? sq[2]   : sq[3];
        float mean = svv * (1.f / 256.f);
        float var = qv * (1.f / 256.f) - mean * mean;
        s_mu[w * 16 + g * 4 + l15] = mean;
        s_iv[w * 16 + g * 4 + l15] = 1.f / sqrtf(var + 1e-5f);
    }
    __syncthreads();

    const float mu_m = s_mu[w * 16 + l15];
    const float iv_m = s_iv[w * 16 + l15];
    const int4* B2 = reinterpret_cast<const int4*>(w2p);
    const unsigned short* trow = s_ts + (w * 16 + l15) * 264;

    f32x4 acc2[8];
    #pragma unroll
    for (int t = 0; t < 8; ++t) acc2[t] = (f32x4){0.f, 0.f, 0.f, 0.f};

    #pragma unroll 2
    for (int kk = 0; kk < 8; ++kk) {
        const int kb = kk * 32 + g * 8;
        int4 traw = *reinterpret_cast<const int4*>(trow + kb);
        const unsigned short* tu = reinterpret_cast<const unsigned short*>(&traw);
        short8 af;
        #pragma unroll
        for (int j = 0; j < 8; ++j) {
            float tv = __uint_as_float(((unsigned int)tu[j]) << 16);
            float rn = fmaxf(fmaf((tv - mu_m) * iv_m, s_lng[kb + j], s_lnb[kb + j]), 0.f);
            af[j] = (short)f2bf(rn);
        }
        #pragma unroll
        for (int t = 0; t < 8; ++t) {
            Frag16B b; b.i = B2[(kk * 8 + t) * 64 + lane];
            acc2[t] = __builtin_amdgcn_mfma_f32_16x16x32_bf16(af, b.s, acc2[t], 0, 0, 0);
        }
    }

    float b2v[8];
    #pragma unroll
    for (int t = 0; t < 8; ++t) b2v[t] = b2[t * 16 + l15];

    #pragma unroll
    for (int t = 0; t < 8; ++t) {
        #pragma unroll
        for (int r = 0; r < 4; ++r) {
            int n = n0 + w * 16 + g * 4 + r;
            if (n < NN)
                out[(size_t)n * 128 + t * 16 + l15] = acc2[t][r] + b2v[t];
        }
    }
}

// ---------------------------------------------------------------------------
extern "C" void kernel_launch(void* const* d_in, const int* in_sizes, int n_in,
                              void* d_out, int out_size, void* d_ws, size_t ws_size,
                              hipStream_t stream)
{
    const float* x    = (const float*)d_in[0];
    const int*   ei   = (const int*)d_in[1];
    const float* pos  = (const float*)d_in[2];
    const float* wft  = (const float*)d_in[3];
    const float* bft  = (const float*)d_in[4];
    const float* wcv  = (const float*)d_in[5];
    const float* bcv  = (const float*)d_in[6];
    const float* vfp  = (const float*)d_in[7];
    const float* vpar = (const float*)d_in[8];
    const float* bng  = (const float*)d_in[9];
    const float* bnbe = (const float*)d_in[10];
    const float* att  = (const float*)d_in[11];
    const float* w1   = (const float*)d_in[12];
    const float* b1   = (const float*)d_in[13];
    const float* lng  = (const float*)d_in[14];
    const float* lnb  = (const float*)d_in[15];
    const float* w2   = (const float*)d_in[16];
    const float* b2   = (const float*)d_in[17];
    float* out = (float*)d_out;

    float* ws = (float*)d_ws;
    size_t off = 0;
    unsigned int* msg  = (unsigned int*)(ws + off); off += (size_t)NN * 64;    // bf16 [N][128]
    unsigned int* aggb = (unsigned int*)(ws + off); off += (size_t)NN * 256;   // bf16 [N][512]
    unsigned short* w1p  = (unsigned short*)(ws + off); off += 65536;
    unsigned short* w2p  = (unsigned short*)(ws + off); off += 16384;
    unsigned short* wftp = (unsigned short*)(ws + off); off += 8192;
    unsigned short* wcvp = (unsigned short*)(ws + off); off += 8192;
    float4* pos4 = (float4*)(ws + off); off += (size_t)NN * 4;
    float* bns  = ws + off; off += 512;
    float* bnbv = ws + off; off += 512;
    float4* dde = (float4*)(ws + off); off += (size_t)EE * 4;   // {dist,dsum,s,d}
    uint4* csre = (uint4*)(ws + off); off += (size_t)EE * 4;    // {src, ab01, ab23, pad}
    int* offs   = (int*)(ws + off); off += NN + 4;
    int* loc    = (int*)(ws + off); off += NN;
    int* bsum   = (int*)(ws + off); off += 256;
    int* bofs   = (int*)(ws + off); off += 256;
    float* blockmax = ws + off; off += 3136;
    float* dmax = ws + off; off += 4;
    size_t zstart = off;
    float* bn_sum = ws + off; off += 512;
    float* bn_sq  = ws + off; off += 512;
    int* counts = (int*)(ws + off); off += NN;
    int* cursor = (int*)(ws + off); off += NN;
    size_t zend = off;

    hipMemsetAsync(ws + zstart, 0, (zend - zstart) * sizeof(float), stream);

    k_prep<<<196, 256, 0, stream>>>(w1, att, w2, wft, wcv, pos, w1p, w2p, wftp, wcvp, pos4);
    k_ft_conv<<<782, 256, 0, stream>>>(x, wftp, bft, wcvp, bcv, msg);
    k_edge_pass1<<<3125, 256, 0, stream>>>(ei, pos4, blockmax, counts, dde);
    k_scan1<<<196, 256, 0, stream>>>(counts, loc, bsum);
    k_scan2dmax<<<2, 256, 0, stream>>>(bsum, bofs, 196, blockmax, dmax, 3125);
    k_scan3<<<196, 256, 0, stream>>>(loc, bofs, offs);
    k_fill<<<3125, 256, 0, stream>>>(dde, dmax, vfp, vpar, offs, cursor, csre);
    k_agg<<<12500, 256, 0, stream>>>(offs, csre, msg, aggb);
    k_bnstats<<<392, 256, 0, stream>>>(aggb, bn_sum, bn_sq);
    k_bnfin<<<2, 256, 0, stream>>>(bn_sum, bn_sq, bng, bnbe, bns, bnbv);
    k_final<<<782, 256, 0, stream>>>(aggb, bns, bnbv, w1p, b1, lng, lnb, w2p, b2, out);
}